// Round 1
// baseline (1298.982 us; speedup 1.0000x reference)
//
#include <hip/hip_runtime.h>

// ChebClassifier: 3 ChebConv(K=6) levels + 2 pools + linear head. All fp32.
// Strategy R0: correctness-first. Atomic-scatter props, tiled fp32 GEMMs,
// incremental out-accumulation to keep workspace ~71 MB (aliased buffers).

namespace {
constexpr int cN0 = 100000, cN1 = 25000, cN2 = 6250;
constexpr int cE0 = 600000, cE1 = 150000, cE2 = 37500;
constexpr int cD  = cN2 * 256;  // 1,600,000
}

__global__ void zero_kernel(float* __restrict__ p, int n) {
  int i = blockIdx.x * blockDim.x + threadIdx.x;
  if (i < n) p[i] = 0.f;
}

__global__ void deg_kernel(const int* __restrict__ src, int E, float* __restrict__ deg) {
  int i = blockIdx.x * blockDim.x + threadIdx.x;
  if (i < E) atomicAdd(&deg[src[i]], 1.0f);
}

__global__ void dinv_kernel(float* __restrict__ d, int n) {
  int i = blockIdx.x * blockDim.x + threadIdx.x;
  if (i < n) {
    float v = d[i];
    d[i] = (v > 0.f) ? rsqrtf(fmaxf(v, 1.f)) : 0.f;
  }
}

__global__ void edgew_kernel(const int* __restrict__ src, const int* __restrict__ dst,
                             const float* __restrict__ dinv, float* __restrict__ w, int E) {
  int i = blockIdx.x * blockDim.x + threadIdx.x;
  if (i < E) w[i] = -(dinv[src[i]] * dinv[dst[i]]);
}

__global__ void negcopy_kernel(const float* __restrict__ a, float* __restrict__ b, int n) {
  int i = blockIdx.x * blockDim.x + threadIdx.x;
  if (i < n) b[i] = -a[i];
}

// y[dst[e]*F + f] += scale * w[e] * h[src[e]*F + f]
template <int F>
__global__ void prop_kernel(const int* __restrict__ src, const int* __restrict__ dst,
                            const float* __restrict__ w, const float* __restrict__ h,
                            float* __restrict__ y, int E, float scale) {
  int idx = blockIdx.x * blockDim.x + threadIdx.x;
  int e = idx / F;
  int f = idx - e * F;
  if (e < E) {
    float v = scale * w[e] * h[(size_t)src[e] * F + f];
    atomicAdd(&y[(size_t)dst[e] * F + f], v);
  }
}

// y[rows[e]*128 + f] += vals[e] * x[cols[e]*128 + f]
__global__ void pool_kernel(const int* __restrict__ rows, const int* __restrict__ cols,
                            const float* __restrict__ vals, const float* __restrict__ x,
                            float* __restrict__ y, int nnz) {
  int idx = blockIdx.x * blockDim.x + threadIdx.x;
  int e = idx >> 7;
  int f = idx & 127;
  if (e < nnz) {
    atomicAdd(&y[(size_t)rows[e] * 128 + f], vals[e] * x[(size_t)cols[e] * 128 + f]);
  }
}

// C[M,N] (+)= A[M,3] @ W[3,N]; init -> start from bias, relu on final k.
__global__ void gemm_k3_kernel(const float* __restrict__ A, const float* __restrict__ W,
                               float* __restrict__ C, const float* __restrict__ bias,
                               int M, int N, int initFlag, int reluFlag) {
  int idx = blockIdx.x * blockDim.x + threadIdx.x;
  int perRow = N >> 2;
  int r = idx / perRow;
  int c4 = (idx - r * perRow) << 2;
  if (r >= M) return;
  float4 acc = initFlag ? *(const float4*)(bias + c4)
                        : *(const float4*)(C + (size_t)r * N + c4);
  float a0 = A[(size_t)r * 3 + 0];
  float a1 = A[(size_t)r * 3 + 1];
  float a2 = A[(size_t)r * 3 + 2];
  float4 w0 = *(const float4*)(W + 0 * N + c4);
  float4 w1 = *(const float4*)(W + 1 * N + c4);
  float4 w2 = *(const float4*)(W + 2 * N + c4);
  acc.x += a0 * w0.x + a1 * w1.x + a2 * w2.x;
  acc.y += a0 * w0.y + a1 * w1.y + a2 * w2.y;
  acc.z += a0 * w0.z + a1 * w1.z + a2 * w2.z;
  acc.w += a0 * w0.w + a1 * w1.w + a2 * w2.w;
  if (reluFlag) {
    acc.x = fmaxf(acc.x, 0.f); acc.y = fmaxf(acc.y, 0.f);
    acc.z = fmaxf(acc.z, 0.f); acc.w = fmaxf(acc.w, 0.f);
  }
  *(float4*)(C + (size_t)r * N + c4) = acc;
}

// C[M,N] (+)= A[M,128] @ W[128,N]. Tile 16 rows x 64 cols, 256 threads,
// each thread 1 row x 4 cols (float4). LDS-staged A (16x32) and W (32x64).
__global__ __launch_bounds__(256) void gemm_k128_kernel(
    const float* __restrict__ A, const float* __restrict__ W,
    float* __restrict__ C, const float* __restrict__ bias,
    int M, int N, int initFlag, int reluFlag) {
  __shared__ float As[16][33];
  __shared__ float Ws[32][68];
  const int tid = threadIdx.x;
  const int rowBase = blockIdx.x * 16;
  const int colBase = blockIdx.y * 64;
  const int tr = tid >> 4;   // 0..15
  const int tc = tid & 15;   // 0..15 -> cols tc*4
  float4 acc = make_float4(0.f, 0.f, 0.f, 0.f);
  for (int k0 = 0; k0 < 128; k0 += 32) {
#pragma unroll
    for (int l = 0; l < 2; ++l) {
      int lin = tid + l * 256;
      int ar = lin >> 5, ak = lin & 31;
      int r = rowBase + ar;
      As[ar][ak] = (r < M) ? A[(size_t)r * 128 + k0 + ak] : 0.f;
    }
#pragma unroll
    for (int l = 0; l < 2; ++l) {
      int lin = tid + l * 256;
      int wr = lin >> 4, wc = (lin & 15) << 2;
      float4 wv = *(const float4*)(W + (size_t)(k0 + wr) * N + colBase + wc);
      *(float4*)&Ws[wr][wc] = wv;
    }
    __syncthreads();
#pragma unroll
    for (int k = 0; k < 32; ++k) {
      float a = As[tr][k];
      float4 wv = *(const float4*)&Ws[k][tc << 2];
      acc.x += a * wv.x; acc.y += a * wv.y;
      acc.z += a * wv.z; acc.w += a * wv.w;
    }
    __syncthreads();
  }
  int r = rowBase + tr;
  if (r < M) {
    float* cp = C + (size_t)r * N + colBase + (tc << 2);
    float4 base = initFlag ? *(const float4*)(bias + colBase + (tc << 2))
                           : *(const float4*)cp;
    acc.x += base.x; acc.y += base.y; acc.z += base.z; acc.w += base.w;
    if (reluFlag) {
      acc.x = fmaxf(acc.x, 0.f); acc.y = fmaxf(acc.y, 0.f);
      acc.z = fmaxf(acc.z, 0.f); acc.w = fmaxf(acc.w, 0.f);
    }
    *(float4*)cp = acc;
  }
}

__global__ void initout_kernel(float* __restrict__ out, const float* __restrict__ linb) {
  int i = threadIdx.x;
  if (i < 10) out[i] = linb[i];
}

__global__ __launch_bounds__(256) void linear_kernel(const float* __restrict__ Wl,
                                                     const float* __restrict__ h,
                                                     float* __restrict__ out, int D) {
  float p[10];
#pragma unroll
  for (int j = 0; j < 10; ++j) p[j] = 0.f;
  int stride = gridDim.x * blockDim.x;
  for (int i = blockIdx.x * blockDim.x + threadIdx.x; i < D; i += stride) {
    float hv = h[i];
#pragma unroll
    for (int j = 0; j < 10; ++j) p[j] += Wl[(size_t)j * D + i] * hv;
  }
#pragma unroll
  for (int j = 0; j < 10; ++j) {
#pragma unroll
    for (int off = 32; off > 0; off >>= 1) p[j] += __shfl_down(p[j], off, 64);
  }
  __shared__ float s[4][10];
  int wave = threadIdx.x >> 6, lane = threadIdx.x & 63;
  if (lane == 0) {
#pragma unroll
    for (int j = 0; j < 10; ++j) s[wave][j] = p[j];
  }
  __syncthreads();
  if (threadIdx.x < 10) {
    float t = s[0][threadIdx.x] + s[1][threadIdx.x] + s[2][threadIdx.x] + s[3][threadIdx.x];
    atomicAdd(&out[threadIdx.x], t);
  }
}

extern "C" void kernel_launch(void* const* d_in, const int* in_sizes, int n_in,
                              void* d_out, int out_size, void* d_ws, size_t ws_size,
                              hipStream_t stream) {
  const float* x    = (const float*)d_in[0];
  const int*   ei0  = (const int*)d_in[1];
  const int*   ei1  = (const int*)d_in[2];
  const int*   ei2  = (const int*)d_in[3];
  const float* W0   = (const float*)d_in[4];
  const float* b0   = (const float*)d_in[5];
  const float* W1   = (const float*)d_in[6];
  const float* b1   = (const float*)d_in[7];
  const float* W2   = (const float*)d_in[8];
  const float* b2   = (const float*)d_in[9];
  const int*   D0r  = (const int*)d_in[10];
  const int*   D0c  = (const int*)d_in[11];
  const float* D0v  = (const float*)d_in[12];
  const int*   D1r  = (const int*)d_in[13];
  const int*   D1c  = (const int*)d_in[14];
  const float* D1v  = (const float*)d_in[15];
  const float* linW = (const float*)d_in[16];
  const float* linb = (const float*)d_in[17];
  float* out = (float*)d_out;

  // ---- workspace layout (floats), 64-elt aligned bump allocator ----
  float* ws = (float*)d_ws;
  size_t off = 0;
  auto alloc = [&](size_t n) {
    float* p = ws + off;
    off += (n + 63) & ~size_t(63);
    return p;
  };
  float* dinv0 = alloc(cN0);
  float* dinv1 = alloc(cN1);
  float* dinv2 = alloc(cN2);
  float* w0buf = alloc(cE0);
  float* w1buf = alloc(cE1);
  float* w2buf = alloc(cE2);
  float* A0 = alloc((size_t)cN0 * 3);
  float* B0 = alloc((size_t)cN0 * 3);
  float* C0 = alloc((size_t)cN0 * 3);
  float* big = alloc((size_t)cN0 * 128);        // 12.8M floats: out0/h0, then level1/2 bufs
  float* pooled1 = alloc((size_t)cN1 * 128);    // 3.2M floats; later reused as pooled2
  (void)ws_size; (void)in_sizes; (void)n_in; (void)out_size;

  // aliases (see dependency analysis in commit journal):
  float* out0 = big;                     // [N0,128] -> h0 after relu
  float* A1 = big + 0;                   // [N1,128]
  float* B1 = big + 3200000;             // [N1,128]
  float* C1 = big + 6400000;             // [N1,128]
  float* out1 = big + 9600000;           // [N1,128] -> h1
  float* A2 = big + 0;                   // [N2,128]
  float* B2 = big + 800000;              // [N2,128]
  float* C2 = big + 1600000;             // [N2,128]
  float* out2 = big + 3200000;           // [N2,256] (final conv out, no relu)
  float* pooled2 = pooled1;              // [N2,128]

  auto nb = [](long long n) { return (unsigned)((n + 255) / 256); };

  // ================= Level 0: F_in=3, F_out=128 =================
  {
    const int* src = ei0;
    const int* dst = ei0 + cE0;
    zero_kernel<<<nb(cN0), 256, 0, stream>>>(dinv0, cN0);
    deg_kernel<<<nb(cE0), 256, 0, stream>>>(src, cE0, dinv0);
    dinv_kernel<<<nb(cN0), 256, 0, stream>>>(dinv0, cN0);
    edgew_kernel<<<nb(cE0), 256, 0, stream>>>(src, dst, dinv0, w0buf, cE0);

    auto gemm3 = [&](const float* Ain, int k, int init, int relu) {
      gemm_k3_kernel<<<nb((long long)cN0 * 32), 256, 0, stream>>>(
          Ain, W0 + (size_t)k * 3 * 128, out0, b0, cN0, 128, init, relu);
    };
    auto prop3 = [&](const float* hin, float* yout, float scale) {
      prop_kernel<3><<<nb((long long)cE0 * 3), 256, 0, stream>>>(
          src, dst, w0buf, hin, yout, cE0, scale);
    };
    auto negc = [&](const float* a, float* b) {
      negcopy_kernel<<<nb((long long)cN0 * 3), 256, 0, stream>>>(a, b, cN0 * 3);
    };

    zero_kernel<<<nb((long long)cN0 * 3), 256, 0, stream>>>(A0, cN0 * 3);
    prop3(x, A0, 1.f);                 // A0 = T1
    gemm3(x, 0, 1, 0);                 // out0 = b0 + T0 @ W0[0]
    gemm3(A0, 1, 0, 0);                // += T1 @ W0[1]
    negc(x, B0);  prop3(A0, B0, 2.f);  gemm3(B0, 2, 0, 0);  // B0 = T2
    negc(A0, C0); prop3(B0, C0, 2.f);  gemm3(C0, 3, 0, 0);  // C0 = T3
    negc(B0, A0); prop3(C0, A0, 2.f);  gemm3(A0, 4, 0, 0);  // A0 = T4
    negc(C0, B0); prop3(A0, B0, 2.f);  gemm3(B0, 5, 0, 1);  // B0 = T5, relu -> h0
  }

  // pool0: h0 [N0,128] -> pooled1 [N1,128]
  zero_kernel<<<nb((long long)cN1 * 128), 256, 0, stream>>>(pooled1, cN1 * 128);
  pool_kernel<<<nb((long long)100000 * 128), 256, 0, stream>>>(D0r, D0c, D0v, out0, pooled1, 100000);

  // ================= generic F_in=128 Cheb level =================
  auto cheb128 = [&](const float* X, const int* ei, int Nn, int E,
                     const float* Wc, const float* bc, float* dinv, float* wbuf,
                     float* Ab, float* Bb, float* Cb, float* Co, int Nout, int relu) {
    const int* src = ei;
    const int* dst = ei + E;
    zero_kernel<<<nb(Nn), 256, 0, stream>>>(dinv, Nn);
    deg_kernel<<<nb(E), 256, 0, stream>>>(src, E, dinv);
    dinv_kernel<<<nb(Nn), 256, 0, stream>>>(dinv, Nn);
    edgew_kernel<<<nb(E), 256, 0, stream>>>(src, dst, dinv, wbuf, E);

    auto gemm = [&](const float* Ain, int k, int init, int rl) {
      dim3 g((Nn + 15) / 16, Nout / 64);
      gemm_k128_kernel<<<g, 256, 0, stream>>>(
          Ain, Wc + (size_t)k * 128 * Nout, Co, bc, Nn, Nout, init, rl);
    };
    auto prop = [&](const float* hin, float* yout, float scale) {
      prop_kernel<128><<<nb((long long)E * 128), 256, 0, stream>>>(
          src, dst, wbuf, hin, yout, E, scale);
    };
    auto negc = [&](const float* a, float* b) {
      negcopy_kernel<<<nb((long long)Nn * 128), 256, 0, stream>>>(a, b, Nn * 128);
    };

    zero_kernel<<<nb((long long)Nn * 128), 256, 0, stream>>>(Ab, Nn * 128);
    prop(X, Ab, 1.f);                  // Ab = T1
    gemm(X, 0, 1, 0);
    gemm(Ab, 1, 0, 0);
    negc(X, Bb);  prop(Ab, Bb, 2.f);  gemm(Bb, 2, 0, 0);
    negc(Ab, Cb); prop(Bb, Cb, 2.f);  gemm(Cb, 3, 0, 0);
    negc(Bb, Ab); prop(Cb, Ab, 2.f);  gemm(Ab, 4, 0, 0);
    negc(Cb, Bb); prop(Ab, Bb, 2.f);  gemm(Bb, 5, 0, relu);
  };

  // Level 1: pooled1 -> h1 (=out1), relu
  cheb128(pooled1, ei1, cN1, cE1, W1, b1, dinv1, w1buf, A1, B1, C1, out1, 128, 1);

  // pool1: h1 [N1,128] -> pooled2 [N2,128]  (pooled1 dead by now)
  zero_kernel<<<nb((long long)cN2 * 128), 256, 0, stream>>>(pooled2, cN2 * 128);
  pool_kernel<<<nb((long long)25000 * 128), 256, 0, stream>>>(D1r, D1c, D1v, out1, pooled2, 25000);

  // Level 2: pooled2 -> out2 [N2,256], no relu
  cheb128(pooled2, ei2, cN2, cE2, W2, b2, dinv2, w2buf, A2, B2, C2, out2, 256, 0);

  // Linear head: out = linW @ out2.flatten() + linb
  initout_kernel<<<1, 64, 0, stream>>>(out, linb);
  linear_kernel<<<512, 256, 0, stream>>>(linW, out2, out, cD);
}

// Round 2
// 927.307 us; speedup vs baseline: 1.4008x; 1.4008x over previous
//
#include <hip/hip_runtime.h>

// ChebClassifier R2: CSR(gather) props with fused recurrence, fused K=18
// level-0 GEMM, 64x64-tile fp32 GEMM for K=128 levels. No atomics on the
// feature paths; atomics only in histograms/scatter (int, low contention).

namespace {
constexpr int cN0 = 100000, cN1 = 25000, cN2 = 6250;
constexpr int cE0 = 600000, cE1 = 150000, cE2 = 37500;
constexpr int cD  = cN2 * 256;  // 1,600,000
}

// ---------------- tiny utility kernels ----------------
__global__ void zero_f_kernel(float* __restrict__ p, int n) {
  int i = blockIdx.x * blockDim.x + threadIdx.x;
  if (i < n) p[i] = 0.f;
}
__global__ void zero_i_kernel(int* __restrict__ p, int n) {
  int i = blockIdx.x * blockDim.x + threadIdx.x;
  if (i < n) p[i] = 0;
}
__global__ void deg_kernel(const int* __restrict__ src, int E, float* __restrict__ deg) {
  int i = blockIdx.x * blockDim.x + threadIdx.x;
  if (i < E) atomicAdd(&deg[src[i]], 1.0f);
}
__global__ void dinv_kernel(float* __restrict__ d, int n) {
  int i = blockIdx.x * blockDim.x + threadIdx.x;
  if (i < n) {
    float v = d[i];
    d[i] = (v > 0.f) ? rsqrtf(fmaxf(v, 1.f)) : 0.f;
  }
}
__global__ void copyx_kernel(const float* __restrict__ x, float* __restrict__ Tb, int n3) {
  int i = blockIdx.x * blockDim.x + threadIdx.x;
  if (i < n3) {
    int r = i / 3, c = i - r * 3;
    Tb[(size_t)r * 18 + c] = x[i];
  }
}

// ---------------- CSR build: hist -> scan -> scatter ----------------
__global__ void hist_kernel(const int* __restrict__ idx, int* __restrict__ cnt, int E) {
  int i = blockIdx.x * blockDim.x + threadIdx.x;
  if (i < E) atomicAdd(&cnt[idx[i]], 1);
}

// exclusive scan over n elements (counts has n-1 real entries; virtual last = 0)
__global__ void scan1_kernel(const int* __restrict__ cnt, int* __restrict__ off,
                             int* __restrict__ bsum, int n) {
  __shared__ int s[256];
  int tid = threadIdx.x;
  int i = blockIdx.x * 256 + tid;
  int v = (i < n - 1) ? cnt[i] : 0;
  s[tid] = v;
  __syncthreads();
  for (int d = 1; d < 256; d <<= 1) {
    int t = (tid >= d) ? s[tid - d] : 0;
    __syncthreads();
    s[tid] += t;
    __syncthreads();
  }
  if (i < n) off[i] = s[tid] - v;  // exclusive within block
  if (tid == 255) bsum[blockIdx.x] = s[255];
}

__global__ void scan2_kernel(const int* __restrict__ bsum, int* __restrict__ boff, int nB) {
  __shared__ int s[512];
  int tid = threadIdx.x;
  int v = (tid < nB) ? bsum[tid] : 0;
  s[tid] = v;
  __syncthreads();
  for (int d = 1; d < 512; d <<= 1) {
    int t = (tid >= d) ? s[tid - d] : 0;
    __syncthreads();
    s[tid] += t;
    __syncthreads();
  }
  boff[tid] = s[tid] - v;  // exclusive
}

__global__ void addoff_kernel(int* __restrict__ off, const int* __restrict__ boff,
                              int* __restrict__ cursor, int n) {
  int i = blockIdx.x * 256 + threadIdx.x;
  if (i < n) {
    int v = off[i] + boff[i >> 8];
    off[i] = v;
    if (i < n - 1) cursor[i] = v;
  }
}

// mode 0: graph (w = -dinv[s]*dinv[d]); mode 1: pool (w = vals[e])
__global__ void scatter_kernel(const int* __restrict__ a, const int* __restrict__ b,
                               const float* __restrict__ dv, int mode,
                               int* __restrict__ cursor, int* __restrict__ csrc,
                               float* __restrict__ cw, int E) {
  int e = blockIdx.x * blockDim.x + threadIdx.x;
  if (e < E) {
    int d = a[e], s = b[e];
    int pos = atomicAdd(&cursor[d], 1);
    csrc[pos] = s;
    cw[pos] = mode ? dv[e] : -(dv[s] * dv[d]);
  }
}

// ---------------- CSR gather props (fused Cheb recurrence) ----------------
// y[r*ys+yo+f] = scale * sum_j cw[j]*h[csrc[j]*hs+ho+f]  (- prev[r*ps+po+f])
__global__ __launch_bounds__(256) void csr_prop128_kernel(
    const int* __restrict__ off, const int* __restrict__ csrc, const float* __restrict__ cw,
    const float* __restrict__ h, float* __restrict__ y,
    const float* __restrict__ prev, float scale, int N) {
  int r = blockIdx.x * 2 + (threadIdx.x >> 7);
  int f = threadIdx.x & 127;
  if (r >= N) return;
  int s = off[r], e = off[r + 1];
  float acc = 0.f;
  for (int j = s; j < e; ++j)
    acc += cw[j] * h[(size_t)csrc[j] * 128 + f];
  float v = scale * acc;
  if (prev) v -= prev[(size_t)r * 128 + f];
  y[(size_t)r * 128 + f] = v;
}

// F=3 variant, one thread per row; strided in/out slices of Tbuf [N,18]
__global__ void csr_prop3_kernel(const int* __restrict__ off, const int* __restrict__ csrc,
                                 const float* __restrict__ cw,
                                 const float* __restrict__ h, int hs, int ho,
                                 float* __restrict__ y, int yo,
                                 const float* __restrict__ prev, int po,
                                 float scale, int N) {
  int r = blockIdx.x * blockDim.x + threadIdx.x;
  if (r >= N) return;
  int s = off[r], e = off[r + 1];
  float a0 = 0.f, a1 = 0.f, a2 = 0.f;
  for (int j = s; j < e; ++j) {
    float w = cw[j];
    const float* hp = h + (size_t)csrc[j] * hs + ho;
    a0 += w * hp[0];
    a1 += w * hp[1];
    a2 += w * hp[2];
  }
  a0 *= scale; a1 *= scale; a2 *= scale;
  if (prev) {
    const float* pp = prev + (size_t)r * 18 + po;
    a0 -= pp[0]; a1 -= pp[1]; a2 -= pp[2];
  }
  float* yp = y + (size_t)r * 18 + yo;
  yp[0] = a0; yp[1] = a1; yp[2] = a2;
}

// ---------------- GEMMs ----------------
// Level 0: C[M,128] = relu(bias + Tb[M,18] @ W[18,128])
__global__ __launch_bounds__(256) void gemm18_kernel(
    const float* __restrict__ Tb, const float* __restrict__ W,
    const float* __restrict__ bias, float* __restrict__ C, int M) {
  __shared__ float Wl[18 * 128];
  for (int i = threadIdx.x; i < 18 * 128; i += 256) Wl[i] = W[i];
  __syncthreads();
  int idx = blockIdx.x * 256 + threadIdx.x;
  int r = idx >> 5;
  int c4 = (idx & 31) << 2;
  if (r >= M) return;
  const float* a = Tb + (size_t)r * 18;
  float4 acc = *(const float4*)(bias + c4);
#pragma unroll
  for (int t = 0; t < 18; ++t) {
    float av = a[t];
    float4 wv = *(const float4*)&Wl[t * 128 + c4];
    acc.x += av * wv.x; acc.y += av * wv.y;
    acc.z += av * wv.z; acc.w += av * wv.w;
  }
  acc.x = fmaxf(acc.x, 0.f); acc.y = fmaxf(acc.y, 0.f);
  acc.z = fmaxf(acc.z, 0.f); acc.w = fmaxf(acc.w, 0.f);
  *(float4*)(C + (size_t)r * 128 + c4) = acc;
}

// C[M,N] (+)= A[M,128] @ W[128,N]; 64x64 tile, 256 thr, 4x4/thread.
__global__ __launch_bounds__(256) void gemm_k128_kernel(
    const float* __restrict__ A, const float* __restrict__ W,
    float* __restrict__ C, const float* __restrict__ bias,
    int M, int N, int initFlag, int reluFlag) {
  __shared__ float Ast[32][68];  // transposed A: [k][row], stride 68 (16B-aligned rows)
  __shared__ float Ws[32][68];   // [k][col]
  const int tid = threadIdx.x;
  const int rowBase = blockIdx.x * 64;
  const int colBase = blockIdx.y * 64;
  const int ty = tid >> 4;  // 0..15 -> rows ty*4..+3
  const int tx = tid & 15;  // 0..15 -> cols tx*4..+3
  float4 acc[4];
#pragma unroll
  for (int i = 0; i < 4; ++i) acc[i] = make_float4(0.f, 0.f, 0.f, 0.f);

  for (int k0 = 0; k0 < 128; k0 += 32) {
#pragma unroll
    for (int l = 0; l < 2; ++l) {
      int lin = tid + l * 256;
      int arow = lin >> 3;          // 0..63
      int ak4 = (lin & 7) << 2;     // 0..28
      int row = rowBase + arow;
      float4 av = make_float4(0.f, 0.f, 0.f, 0.f);
      if (row < M) av = *(const float4*)(A + (size_t)row * 128 + k0 + ak4);
      Ast[ak4 + 0][arow] = av.x;
      Ast[ak4 + 1][arow] = av.y;
      Ast[ak4 + 2][arow] = av.z;
      Ast[ak4 + 3][arow] = av.w;
    }
#pragma unroll
    for (int l = 0; l < 2; ++l) {
      int lin = tid + l * 256;
      int wk = lin >> 4;            // 0..31
      int wc4 = (lin & 15) << 2;    // 0..60
      float4 wv = *(const float4*)(W + (size_t)(k0 + wk) * N + colBase + wc4);
      *(float4*)&Ws[wk][wc4] = wv;
    }
    __syncthreads();
#pragma unroll
    for (int k = 0; k < 32; ++k) {
      float4 av = *(const float4*)&Ast[k][ty << 2];
      float4 wv = *(const float4*)&Ws[k][tx << 2];
      acc[0].x += av.x * wv.x; acc[0].y += av.x * wv.y; acc[0].z += av.x * wv.z; acc[0].w += av.x * wv.w;
      acc[1].x += av.y * wv.x; acc[1].y += av.y * wv.y; acc[1].z += av.y * wv.z; acc[1].w += av.y * wv.w;
      acc[2].x += av.z * wv.x; acc[2].y += av.z * wv.y; acc[2].z += av.z * wv.z; acc[2].w += av.z * wv.w;
      acc[3].x += av.w * wv.x; acc[3].y += av.w * wv.y; acc[3].z += av.w * wv.z; acc[3].w += av.w * wv.w;
    }
    __syncthreads();
  }

#pragma unroll
  for (int i = 0; i < 4; ++i) {
    int row = rowBase + (ty << 2) + i;
    if (row >= M) continue;
    float* cp = C + (size_t)row * N + colBase + (tx << 2);
    float4 base = initFlag ? *(const float4*)(bias + colBase + (tx << 2))
                           : *(const float4*)cp;
    float4 v = acc[i];
    v.x += base.x; v.y += base.y; v.z += base.z; v.w += base.w;
    if (reluFlag) {
      v.x = fmaxf(v.x, 0.f); v.y = fmaxf(v.y, 0.f);
      v.z = fmaxf(v.z, 0.f); v.w = fmaxf(v.w, 0.f);
    }
    *(float4*)cp = v;
  }
}

// ---------------- linear head ----------------
__global__ void initout_kernel(float* __restrict__ out, const float* __restrict__ linb) {
  int i = threadIdx.x;
  if (i < 10) out[i] = linb[i];
}

__global__ __launch_bounds__(256) void linear_kernel(const float* __restrict__ Wl,
                                                     const float* __restrict__ h,
                                                     float* __restrict__ out, int D) {
  float p[10];
#pragma unroll
  for (int j = 0; j < 10; ++j) p[j] = 0.f;
  int stride = gridDim.x * blockDim.x;
  for (int i = blockIdx.x * blockDim.x + threadIdx.x; i < D; i += stride) {
    float hv = h[i];
#pragma unroll
    for (int j = 0; j < 10; ++j) p[j] += Wl[(size_t)j * D + i] * hv;
  }
#pragma unroll
  for (int j = 0; j < 10; ++j) {
#pragma unroll
    for (int off = 32; off > 0; off >>= 1) p[j] += __shfl_down(p[j], off, 64);
  }
  __shared__ float s[4][10];
  int wave = threadIdx.x >> 6, lane = threadIdx.x & 63;
  if (lane == 0) {
#pragma unroll
    for (int j = 0; j < 10; ++j) s[wave][j] = p[j];
  }
  __syncthreads();
  if (threadIdx.x < 10) {
    float t = s[0][threadIdx.x] + s[1][threadIdx.x] + s[2][threadIdx.x] + s[3][threadIdx.x];
    atomicAdd(&out[threadIdx.x], t);
  }
}

// ---------------- host orchestration ----------------
extern "C" void kernel_launch(void* const* d_in, const int* in_sizes, int n_in,
                              void* d_out, int out_size, void* d_ws, size_t ws_size,
                              hipStream_t stream) {
  const float* x    = (const float*)d_in[0];
  const int*   ei0  = (const int*)d_in[1];
  const int*   ei1  = (const int*)d_in[2];
  const int*   ei2  = (const int*)d_in[3];
  const float* W0   = (const float*)d_in[4];
  const float* b0   = (const float*)d_in[5];
  const float* W1   = (const float*)d_in[6];
  const float* b1   = (const float*)d_in[7];
  const float* W2   = (const float*)d_in[8];
  const float* b2   = (const float*)d_in[9];
  const int*   D0r  = (const int*)d_in[10];
  const int*   D0c  = (const int*)d_in[11];
  const float* D0v  = (const float*)d_in[12];
  const int*   D1r  = (const int*)d_in[13];
  const int*   D1c  = (const int*)d_in[14];
  const float* D1v  = (const float*)d_in[15];
  const float* linW = (const float*)d_in[16];
  const float* linb = (const float*)d_in[17];
  float* out = (float*)d_out;
  (void)in_sizes; (void)n_in; (void)out_size; (void)ws_size;

  // ---- workspace layout (floats), 64-elt aligned bump allocator (~70.2 MB) ----
  float* ws = (float*)d_ws;
  size_t off = 0;
  auto alloc = [&](size_t n) {
    float* p = ws + off;
    off += (n + 63) & ~size_t(63);
    return p;
  };
  float* dinv0   = alloc(cN0);
  float* dinv1   = alloc(cN1);
  float* dinv2   = alloc(cN2);
  int*   csr_off = (int*)alloc(cN0 + 1);
  int*   csr_cur = (int*)alloc(cN0);
  int*   csr_src = (int*)alloc(cE0);
  float* csr_w   = alloc(cE0);
  int*   bsum    = (int*)alloc(512);
  int*   boff    = (int*)alloc(512);
  float* small_r = alloc((size_t)cN1 * 128);  // Tbuf0 [N0,18] then pooled1/pooled2
  float* big     = alloc((size_t)cN0 * 128);  // out0/h0, then L1/L2 rotation buffers

  float* Tbuf0   = small_r;             // [N0,18] (1.8M <= 3.2M)
  float* pooled1 = small_r;             // [N1,128] (after Tbuf0 dead)
  float* pooled2 = small_r;             // [N2,128] (after pooled1 dead)
  float* out0 = big;                    // [N0,128]
  float* A1 = big + 0;                  // [N1,128]
  float* B1 = big + 3200000;
  float* C1 = big + 6400000;
  float* out1 = big + 9600000;
  float* A2 = big + 0;                  // [N2,128]
  float* B2 = big + 800000;
  float* C2 = big + 1600000;
  float* out2 = big + 3200000;          // [N2,256]

  auto nb = [](long long n) { return (unsigned)((n + 255) / 256); };

  // Build CSR (shared region) for (a -> rows/dst, b -> cols/src)
  auto build_csr = [&](const int* a, const int* b, const float* dv, int mode, int N, int E) {
    zero_i_kernel<<<nb(N), 256, 0, stream>>>(csr_cur, N);
    hist_kernel<<<nb(E), 256, 0, stream>>>(a, csr_cur, E);
    int n = N + 1;
    int nB = (n + 255) / 256;
    scan1_kernel<<<nB, 256, 0, stream>>>(csr_cur, csr_off, bsum, n);
    scan2_kernel<<<1, 512, 0, stream>>>(bsum, boff, nB);
    addoff_kernel<<<nB, 256, 0, stream>>>(csr_off, boff, csr_cur, n);
    scatter_kernel<<<nb(E), 256, 0, stream>>>(a, b, dv, mode, csr_cur, csr_src, csr_w, E);
  };
  auto make_dinv = [&](const int* src, float* dinv, int N, int E) {
    zero_f_kernel<<<nb(N), 256, 0, stream>>>(dinv, N);
    deg_kernel<<<nb(E), 256, 0, stream>>>(src, E, dinv);
    dinv_kernel<<<nb(N), 256, 0, stream>>>(dinv, N);
  };

  // ================= Level 0 (F=3 -> 128) =================
  {
    const int* src = ei0;
    const int* dst = ei0 + cE0;
    make_dinv(src, dinv0, cN0, cE0);
    build_csr(dst, src, dinv0, 0, cN0, cE0);
    copyx_kernel<<<nb((long long)cN0 * 3), 256, 0, stream>>>(x, Tbuf0, cN0 * 3);
    auto prop3 = [&](int hOff, int yOff, int pOff, int hasPrev, float scale) {
      csr_prop3_kernel<<<nb(cN0), 256, 0, stream>>>(
          csr_off, csr_src, csr_w,
          hasPrev ? Tbuf0 : x, hasPrev ? 18 : 3, hasPrev ? hOff : 0,
          Tbuf0, yOff, hasPrev ? Tbuf0 : nullptr, pOff, scale, cN0);
    };
    // T1 from x; T2..T5 from Tbuf slices with fused -prev
    csr_prop3_kernel<<<nb(cN0), 256, 0, stream>>>(csr_off, csr_src, csr_w,
        x, 3, 0, Tbuf0, 3, nullptr, 0, 1.f, cN0);
    prop3(3, 6, 0, 1, 2.f);
    prop3(6, 9, 3, 1, 2.f);
    prop3(9, 12, 6, 1, 2.f);
    prop3(12, 15, 9, 1, 2.f);
    gemm18_kernel<<<nb((long long)cN0 * 32), 256, 0, stream>>>(Tbuf0, W0, b0, out0, cN0);
  }

  // pool0: h0 [N0,128] -> pooled1 [N1,128]
  build_csr(D0r, D0c, D0v, 1, cN1, 100000);
  csr_prop128_kernel<<<nb((long long)cN1 * 128), 256, 0, stream>>>(
      csr_off, csr_src, csr_w, out0, pooled1, nullptr, 1.f, cN1);

  // ================= generic F=128 level =================
  auto cheb128 = [&](const float* X, const int* ei, int Nn, int E,
                     const float* Wc, const float* bc, float* dinv,
                     float* Ab, float* Bb, float* Cb, float* Co, int Nout, int relu) {
    const int* src = ei;
    const int* dst = ei + E;
    make_dinv(src, dinv, Nn, E);
    build_csr(dst, src, dinv, 0, Nn, E);
    auto gemm = [&](const float* Ain, int k, int init, int rl) {
      dim3 g((Nn + 63) / 64, Nout / 64);
      gemm_k128_kernel<<<g, 256, 0, stream>>>(
          Ain, Wc + (size_t)k * 128 * Nout, Co, bc, Nn, Nout, init, rl);
    };
    auto prop = [&](const float* hin, float* yout, const float* prev, float scale) {
      csr_prop128_kernel<<<nb((long long)Nn * 128), 256, 0, stream>>>(
          csr_off, csr_src, csr_w, hin, yout, prev, scale, Nn);
    };
    prop(X, Ab, nullptr, 1.f);     // T1
    gemm(X, 0, 1, 0);
    gemm(Ab, 1, 0, 0);
    prop(Ab, Bb, X, 2.f);  gemm(Bb, 2, 0, 0);   // T2 = 2 L T1 - T0
    prop(Bb, Cb, Ab, 2.f); gemm(Cb, 3, 0, 0);   // T3
    prop(Cb, Ab, Bb, 2.f); gemm(Ab, 4, 0, 0);   // T4 (overwrites T1)
    prop(Ab, Bb, Cb, 2.f); gemm(Bb, 5, 0, relu);// T5
  };

  // Level 1
  cheb128(pooled1, ei1, cN1, cE1, W1, b1, dinv1, A1, B1, C1, out1, 128, 1);

  // pool1: h1 [N1,128] -> pooled2 [N2,128]
  build_csr(D1r, D1c, D1v, 1, cN2, 25000);
  csr_prop128_kernel<<<nb((long long)cN2 * 128), 256, 0, stream>>>(
      csr_off, csr_src, csr_w, out1, pooled2, nullptr, 1.f, cN2);

  // Level 2 (no relu)
  cheb128(pooled2, ei2, cN2, cE2, W2, b2, dinv2, A2, B2, C2, out2, 256, 0);

  // Linear head
  initout_kernel<<<1, 64, 0, stream>>>(out, linb);
  linear_kernel<<<512, 256, 0, stream>>>(linW, out2, out, cD);
}

// Round 3
// 870.631 us; speedup vs baseline: 1.4920x; 1.0651x over previous
//
#include <hip/hip_runtime.h>

// ChebClassifier R3: batched CSR build (6 launches for all 5 graphs),
// contiguous T-stacks + ONE fused K=768 GEMM per 128-feat level,
// 128x128 tile 8x8/thread fp32 GEMM. ~29 launches total. ws = 256 MiB.

namespace {
constexpr int cN0 = 100000, cN1 = 25000, cN2 = 6250;
constexpr int cE0 = 600000, cE1 = 150000, cE2 = 37500;
constexpr int cP0 = 100000, cP1 = 25000;  // pool nnz
constexpr int cD  = cN2 * 256;

// ---- concatenated segment tables (compile-time) ----
// segs: 0=graph0, 1=graph1, 2=graph2, 3=pool0, 4=pool1
constexpr int SEG_N[5]     = {cN0, cN1, cN2, cN1, cN2};
constexpr int SEG_E[5]     = {cE0, cE1, cE2, cP0, cP1};
constexpr int NBASE[5]     = {0, 100096, 125184, 131584, 156672};  // 256-padded
constexpr int NPAD_TOTAL   = 163072;
constexpr int BLKBASE[5]   = {0, 391, 489, 514, 612};
constexpr int BLK_TOTAL    = 637;
constexpr int EBASE[5]     = {0, 600000, 750000, 787500, 887500};
constexpr int E_TOTAL      = 912500;
constexpr int DEGBASE[5]   = {0, 100000, 125000, 0, 0};
constexpr int DEG_TOTAL    = 131250;
}

// ---------------- batched CSR build ----------------
__global__ void zero_all_kernel(int* __restrict__ cnt, int* __restrict__ deg) {
  int i = blockIdx.x * 256 + threadIdx.x;
  if (i < NPAD_TOTAL) cnt[i] = 0;
  if (i < DEG_TOTAL) deg[i] = 0;
}

__global__ void hist_all_kernel(const int* __restrict__ d0, const int* __restrict__ s0,
                                const int* __restrict__ d1, const int* __restrict__ s1,
                                const int* __restrict__ d2, const int* __restrict__ s2,
                                const int* __restrict__ p0r, const int* __restrict__ p1r,
                                int* __restrict__ cnt, int* __restrict__ deg) {
  int e = blockIdx.x * 256 + threadIdx.x;
  if (e >= E_TOTAL) return;
  int seg = (e < EBASE[1]) ? 0 : (e < EBASE[2]) ? 1 : (e < EBASE[3]) ? 2 : (e < EBASE[4]) ? 3 : 4;
  int le = e - EBASE[seg];
  const int* a; const int* b = nullptr;
  if (seg == 0) { a = d0; b = s0; }
  else if (seg == 1) { a = d1; b = s1; }
  else if (seg == 2) { a = d2; b = s2; }
  else if (seg == 3) { a = p0r; }
  else { a = p1r; }
  atomicAdd(&cnt[NBASE[seg] + a[le]], 1);
  if (seg < 3) atomicAdd(&deg[DEGBASE[seg] + b[le]], 1);
}

// per-block exclusive scan within segment; also fold dinv transform
__global__ void scan1_all_kernel(const int* __restrict__ cnt, int* __restrict__ off,
                                 int* __restrict__ bsum, const int* __restrict__ deg,
                                 float* __restrict__ dinv) {
  __shared__ int s[256];
  int blk = blockIdx.x;
  int seg = (blk < BLKBASE[1]) ? 0 : (blk < BLKBASE[2]) ? 1 : (blk < BLKBASE[3]) ? 2
          : (blk < BLKBASE[4]) ? 3 : 4;
  int j = (blk - BLKBASE[seg]) * 256 + threadIdx.x;  // in-seg index
  int N = SEG_N[seg];
  int v = (j < N) ? cnt[NBASE[seg] + j] : 0;
  s[threadIdx.x] = v;
  __syncthreads();
  for (int d = 1; d < 256; d <<= 1) {
    int t = (threadIdx.x >= d) ? s[threadIdx.x - d] : 0;
    __syncthreads();
    s[threadIdx.x] += t;
    __syncthreads();
  }
  off[NBASE[seg] + j] = s[threadIdx.x] - v;  // exclusive (padded region is safe)
  if (threadIdx.x == 255) bsum[blk] = s[255];
  if (seg < 3 && j < N) {
    int dg = deg[DEGBASE[seg] + j];
    dinv[DEGBASE[seg] + j] = (dg > 0) ? rsqrtf((float)dg) : 0.f;
  }
}

__global__ void scan2_all_kernel(const int* __restrict__ bsum, int* __restrict__ boff) {
  __shared__ int s[512];
  int seg = blockIdx.x;
  int nB = ((seg == 4) ? BLK_TOTAL : BLKBASE[seg + 1]) - BLKBASE[seg];
  int v = (threadIdx.x < nB) ? bsum[BLKBASE[seg] + threadIdx.x] : 0;
  s[threadIdx.x] = v;
  __syncthreads();
  for (int d = 1; d < 512; d <<= 1) {
    int t = (threadIdx.x >= d) ? s[threadIdx.x - d] : 0;
    __syncthreads();
    s[threadIdx.x] += t;
    __syncthreads();
  }
  if (threadIdx.x < nB) boff[BLKBASE[seg] + threadIdx.x] = s[threadIdx.x] - v;
}

__global__ void addoff_all_kernel(int* __restrict__ off, const int* __restrict__ boff,
                                  int* __restrict__ cursor) {
  int blk = blockIdx.x;
  int seg = (blk < BLKBASE[1]) ? 0 : (blk < BLKBASE[2]) ? 1 : (blk < BLKBASE[3]) ? 2
          : (blk < BLKBASE[4]) ? 3 : 4;
  int j = (blk - BLKBASE[seg]) * 256 + threadIdx.x;
  int i = NBASE[seg] + j;
  int v = off[i] + boff[blk];
  off[i] = v;
  cursor[i] = v;
}

__global__ void scatter_all_kernel(const int* __restrict__ d0, const int* __restrict__ s0,
                                   const int* __restrict__ d1, const int* __restrict__ s1,
                                   const int* __restrict__ d2, const int* __restrict__ s2,
                                   const int* __restrict__ p0r, const int* __restrict__ p0c,
                                   const float* __restrict__ p0v,
                                   const int* __restrict__ p1r, const int* __restrict__ p1c,
                                   const float* __restrict__ p1v,
                                   const float* __restrict__ dinv,
                                   int* __restrict__ cursor, int* __restrict__ csrc,
                                   float* __restrict__ cw) {
  int e = blockIdx.x * 256 + threadIdx.x;
  if (e >= E_TOTAL) return;
  int seg = (e < EBASE[1]) ? 0 : (e < EBASE[2]) ? 1 : (e < EBASE[3]) ? 2 : (e < EBASE[4]) ? 3 : 4;
  int le = e - EBASE[seg];
  const int* a; const int* b; const float* vv = nullptr;
  if (seg == 0) { a = d0; b = s0; }
  else if (seg == 1) { a = d1; b = s1; }
  else if (seg == 2) { a = d2; b = s2; }
  else if (seg == 3) { a = p0r; b = p0c; vv = p0v; }
  else { a = p1r; b = p1c; vv = p1v; }
  int d = a[le], s = b[le];
  int pos = atomicAdd(&cursor[NBASE[seg] + d], 1);
  float w;
  if (seg < 3) w = -(dinv[DEGBASE[seg] + s] * dinv[DEGBASE[seg] + d]);
  else w = vv[le];
  csrc[EBASE[seg] + pos] = s;
  cw[EBASE[seg] + pos] = w;
}

// ---------------- props ----------------
// y[r,f] = scale * sum_j cw[j]*h[csrc[j],f]  (- prev[r,f]); 128 feats
__global__ __launch_bounds__(256) void csr_prop128_kernel(
    const int* __restrict__ off, const int* __restrict__ csrc, const float* __restrict__ cw,
    const float* __restrict__ h, float* __restrict__ y,
    const float* __restrict__ prev, float scale, int N) {
  int r = blockIdx.x * 2 + (threadIdx.x >> 7);
  int f = threadIdx.x & 127;
  if (r >= N) return;
  int s = off[r], e = off[r + 1];
  float acc = 0.f;
  for (int j = s; j < e; ++j)
    acc += cw[j] * h[(size_t)csrc[j] * 128 + f];
  float v = scale * acc;
  if (prev) v -= prev[(size_t)r * 128 + f];
  y[(size_t)r * 128 + f] = v;
}

// F=3 variant over Tbuf [N,18] slices
__global__ void csr_prop3_kernel(const int* __restrict__ off, const int* __restrict__ csrc,
                                 const float* __restrict__ cw,
                                 const float* __restrict__ h, int hs, int ho,
                                 float* __restrict__ y, int yo,
                                 const float* __restrict__ prev, int po,
                                 float scale, int N) {
  int r = blockIdx.x * blockDim.x + threadIdx.x;
  if (r >= N) return;
  int s = off[r], e = off[r + 1];
  float a0 = 0.f, a1 = 0.f, a2 = 0.f;
  for (int j = s; j < e; ++j) {
    float w = cw[j];
    const float* hp = h + (size_t)csrc[j] * hs + ho;
    a0 += w * hp[0]; a1 += w * hp[1]; a2 += w * hp[2];
  }
  a0 *= scale; a1 *= scale; a2 *= scale;
  if (prev) {
    const float* pp = prev + (size_t)r * 18 + po;
    a0 -= pp[0]; a1 -= pp[1]; a2 -= pp[2];
  }
  float* yp = y + (size_t)r * 18 + yo;
  yp[0] = a0; yp[1] = a1; yp[2] = a2;
}

__global__ void copyx_kernel(const float* __restrict__ x, float* __restrict__ Tb, int n3) {
  int i = blockIdx.x * blockDim.x + threadIdx.x;
  if (i < n3) {
    int r = i / 3, c = i - r * 3;
    Tb[(size_t)r * 18 + c] = x[i];
  }
}

// ---------------- GEMMs ----------------
// Level 0: C[M,128] = relu(bias + Tb[M,18] @ W[18,128])
__global__ __launch_bounds__(256) void gemm18_kernel(
    const float* __restrict__ Tb, const float* __restrict__ W,
    const float* __restrict__ bias, float* __restrict__ C, int M) {
  __shared__ float Wl[18 * 128];
  for (int i = threadIdx.x; i < 18 * 128; i += 256) Wl[i] = W[i];
  __syncthreads();
  int idx = blockIdx.x * 256 + threadIdx.x;
  int r = idx >> 5;
  int c4 = (idx & 31) << 2;
  if (r >= M) return;
  const float* a = Tb + (size_t)r * 18;
  float4 acc = *(const float4*)(bias + c4);
#pragma unroll
  for (int t = 0; t < 18; ++t) {
    float av = a[t];
    float4 wv = *(const float4*)&Wl[t * 128 + c4];
    acc.x += av * wv.x; acc.y += av * wv.y;
    acc.z += av * wv.z; acc.w += av * wv.w;
  }
  acc.x = fmaxf(acc.x, 0.f); acc.y = fmaxf(acc.y, 0.f);
  acc.z = fmaxf(acc.z, 0.f); acc.w = fmaxf(acc.w, 0.f);
  *(float4*)(C + (size_t)r * 128 + c4) = acc;
}

// C[M,N] = act(bias + Tcat[M,768] @ W[768,N]); Tcat stored [6][M][128].
// 128x128 tile, 256 threads, 8x8 per thread.
__global__ __launch_bounds__(256, 2) void gemm_fused_kernel(
    const float* __restrict__ T, const float* __restrict__ W,
    const float* __restrict__ bias, float* __restrict__ C,
    int M, int N, int reluFlag) {
  __shared__ float Ast[32][132];  // [k][row]
  __shared__ float Ws[32][132];   // [k][col]
  const int tid = threadIdx.x;
  const int rowBase = blockIdx.x * 128;
  const int colBase = blockIdx.y * 128;
  const int ty4 = (tid >> 4) << 2;  // 0..60
  const int tx4 = (tid & 15) << 2;  // 0..60
  float4 acc[8][2];
#pragma unroll
  for (int i = 0; i < 8; ++i) {
    acc[i][0] = make_float4(0.f, 0.f, 0.f, 0.f);
    acc[i][1] = make_float4(0.f, 0.f, 0.f, 0.f);
  }
  const size_t Mstride = (size_t)M * 128;

  for (int kchunk = 0; kchunk < 24; ++kchunk) {
    const float* Ab = T + (size_t)(kchunk >> 2) * Mstride;
    const int k0 = (kchunk & 3) << 5;       // 0,32,64,96
    const int kw = (kchunk >> 2) * 128 + k0; // global k for W
    // stage A-chunk (128 rows x 32 k), transposed into Ast
#pragma unroll
    for (int l = 0; l < 4; ++l) {
      int lin = tid + l * 256;
      int arow = lin >> 3;           // 0..127
      int ak4 = (lin & 7) << 2;      // 0..28
      int row = rowBase + arow;
      float4 av = make_float4(0.f, 0.f, 0.f, 0.f);
      if (row < M) av = *(const float4*)(Ab + (size_t)row * 128 + k0 + ak4);
      Ast[ak4 + 0][arow] = av.x;
      Ast[ak4 + 1][arow] = av.y;
      Ast[ak4 + 2][arow] = av.z;
      Ast[ak4 + 3][arow] = av.w;
    }
    // stage W-chunk (32 k x 128 cols)
#pragma unroll
    for (int l = 0; l < 4; ++l) {
      int lin = tid + l * 256;
      int wk = lin >> 5;             // 0..31
      int wc4 = (lin & 31) << 2;     // 0..124
      float4 wv = *(const float4*)(W + (size_t)(kw + wk) * N + colBase + wc4);
      *(float4*)&Ws[wk][wc4] = wv;
    }
    __syncthreads();
#pragma unroll
    for (int k = 0; k < 32; ++k) {
      float4 a0 = *(const float4*)&Ast[k][ty4];
      float4 a1 = *(const float4*)&Ast[k][ty4 + 64];
      float4 b0 = *(const float4*)&Ws[k][tx4];
      float4 b1 = *(const float4*)&Ws[k][tx4 + 64];
      float ar[8] = {a0.x, a0.y, a0.z, a0.w, a1.x, a1.y, a1.z, a1.w};
#pragma unroll
      for (int i = 0; i < 8; ++i) {
        acc[i][0].x += ar[i] * b0.x; acc[i][0].y += ar[i] * b0.y;
        acc[i][0].z += ar[i] * b0.z; acc[i][0].w += ar[i] * b0.w;
        acc[i][1].x += ar[i] * b1.x; acc[i][1].y += ar[i] * b1.y;
        acc[i][1].z += ar[i] * b1.z; acc[i][1].w += ar[i] * b1.w;
      }
    }
    __syncthreads();
  }

  float4 bias0 = *(const float4*)(bias + colBase + tx4);
  float4 bias1 = *(const float4*)(bias + colBase + tx4 + 64);
#pragma unroll
  for (int i = 0; i < 8; ++i) {
    int row = rowBase + ((i < 4) ? (ty4 + i) : (ty4 + 64 + i - 4));
    if (row >= M) continue;
#pragma unroll
    for (int half = 0; half < 2; ++half) {
      float4 v = acc[i][half];
      float4 bb = half ? bias1 : bias0;
      v.x += bb.x; v.y += bb.y; v.z += bb.z; v.w += bb.w;
      if (reluFlag) {
        v.x = fmaxf(v.x, 0.f); v.y = fmaxf(v.y, 0.f);
        v.z = fmaxf(v.z, 0.f); v.w = fmaxf(v.w, 0.f);
      }
      *(float4*)(C + (size_t)row * N + colBase + tx4 + half * 64) = v;
    }
  }
}

// ---------------- linear head ----------------
__global__ void initout_kernel(float* __restrict__ out, const float* __restrict__ linb) {
  int i = threadIdx.x;
  if (i < 10) out[i] = linb[i];
}

__global__ __launch_bounds__(256) void linear_kernel(const float* __restrict__ Wl,
                                                     const float* __restrict__ h,
                                                     float* __restrict__ out, int D) {
  float p[10];
#pragma unroll
  for (int j = 0; j < 10; ++j) p[j] = 0.f;
  int stride = gridDim.x * blockDim.x;
  for (int i = blockIdx.x * blockDim.x + threadIdx.x; i < D; i += stride) {
    float hv = h[i];
#pragma unroll
    for (int j = 0; j < 10; ++j) p[j] += Wl[(size_t)j * D + i] * hv;
  }
#pragma unroll
  for (int j = 0; j < 10; ++j) {
#pragma unroll
    for (int off = 32; off > 0; off >>= 1) p[j] += __shfl_down(p[j], off, 64);
  }
  __shared__ float s[4][10];
  int wave = threadIdx.x >> 6, lane = threadIdx.x & 63;
  if (lane == 0) {
#pragma unroll
    for (int j = 0; j < 10; ++j) s[wave][j] = p[j];
  }
  __syncthreads();
  if (threadIdx.x < 10) {
    float t = s[0][threadIdx.x] + s[1][threadIdx.x] + s[2][threadIdx.x] + s[3][threadIdx.x];
    atomicAdd(&out[threadIdx.x], t);
  }
}

// ---------------- host orchestration ----------------
extern "C" void kernel_launch(void* const* d_in, const int* in_sizes, int n_in,
                              void* d_out, int out_size, void* d_ws, size_t ws_size,
                              hipStream_t stream) {
  const float* x    = (const float*)d_in[0];
  const int*   ei0  = (const int*)d_in[1];
  const int*   ei1  = (const int*)d_in[2];
  const int*   ei2  = (const int*)d_in[3];
  const float* W0   = (const float*)d_in[4];
  const float* b0   = (const float*)d_in[5];
  const float* W1   = (const float*)d_in[6];
  const float* b1   = (const float*)d_in[7];
  const float* W2   = (const float*)d_in[8];
  const float* b2   = (const float*)d_in[9];
  const int*   D0r  = (const int*)d_in[10];
  const int*   D0c  = (const int*)d_in[11];
  const float* D0v  = (const float*)d_in[12];
  const int*   D1r  = (const int*)d_in[13];
  const int*   D1c  = (const int*)d_in[14];
  const float* D1v  = (const float*)d_in[15];
  const float* linW = (const float*)d_in[16];
  const float* linb = (const float*)d_in[17];
  float* out = (float*)d_out;
  (void)in_sizes; (void)n_in; (void)out_size; (void)ws_size;

  const int* src0 = ei0;            const int* dst0 = ei0 + cE0;
  const int* src1 = ei1;            const int* dst1 = ei1 + cE1;
  const int* src2 = ei2;            const int* dst2 = ei2 + cE2;

  // ---- workspace (floats), 64-elt aligned; total ~184 MB of 256 MiB ----
  float* ws = (float*)d_ws;
  size_t off = 0;
  auto alloc = [&](size_t n) {
    float* p = ws + off;
    off += (n + 63) & ~size_t(63);
    return p;
  };
  int*   deg     = (int*)alloc(DEG_TOTAL);
  float* dinv    = alloc(DEG_TOTAL);
  int*   cnt     = (int*)alloc(NPAD_TOTAL);
  int*   offArr  = (int*)alloc(NPAD_TOTAL);
  int*   cursor  = (int*)alloc(NPAD_TOTAL);
  int*   bsum    = (int*)alloc(BLK_TOTAL);
  int*   boff    = (int*)alloc(BLK_TOTAL);
  int*   csrX    = (int*)alloc(E_TOTAL);
  float* csrW    = alloc(E_TOTAL);
  float* Tbuf0   = alloc((size_t)cN0 * 18);
  float* out0    = alloc((size_t)cN0 * 128);
  float* Tlvl1   = alloc((size_t)6 * cN1 * 128);
  float* out1    = alloc((size_t)cN1 * 128);
  float* Tlvl2   = alloc((size_t)6 * cN2 * 128);
  float* out2    = alloc((size_t)cN2 * 256);

  auto nb = [](long long n) { return (unsigned)((n + 255) / 256); };

  // ---- batched CSR build: 6 launches for all 5 graphs ----
  zero_all_kernel<<<nb(NPAD_TOTAL), 256, 0, stream>>>(cnt, deg);
  hist_all_kernel<<<nb(E_TOTAL), 256, 0, stream>>>(dst0, src0, dst1, src1, dst2, src2,
                                                   D0r, D1r, cnt, deg);
  scan1_all_kernel<<<BLK_TOTAL, 256, 0, stream>>>(cnt, offArr, bsum, deg, dinv);
  scan2_all_kernel<<<5, 512, 0, stream>>>(bsum, boff);
  addoff_all_kernel<<<BLK_TOTAL, 256, 0, stream>>>(offArr, boff, cursor);
  scatter_all_kernel<<<nb(E_TOTAL), 256, 0, stream>>>(dst0, src0, dst1, src1, dst2, src2,
                                                      D0r, D0c, D0v, D1r, D1c, D1v,
                                                      dinv, cursor, csrX, csrW);

  // per-seg CSR views
  auto seg_off  = [&](int s) { return offArr + NBASE[s]; };
  auto seg_src  = [&](int s) { return csrX + EBASE[s]; };
  auto seg_w    = [&](int s) { return csrW + EBASE[s]; };

  // ================= Level 0 (F=3 -> 128) =================
  copyx_kernel<<<nb((long long)cN0 * 3), 256, 0, stream>>>(x, Tbuf0, cN0 * 3);
  csr_prop3_kernel<<<nb(cN0), 256, 0, stream>>>(seg_off(0), seg_src(0), seg_w(0),
      x, 3, 0, Tbuf0, 3, nullptr, 0, 1.f, cN0);
  csr_prop3_kernel<<<nb(cN0), 256, 0, stream>>>(seg_off(0), seg_src(0), seg_w(0),
      Tbuf0, 18, 3, Tbuf0, 6, Tbuf0, 0, 2.f, cN0);
  csr_prop3_kernel<<<nb(cN0), 256, 0, stream>>>(seg_off(0), seg_src(0), seg_w(0),
      Tbuf0, 18, 6, Tbuf0, 9, Tbuf0, 3, 2.f, cN0);
  csr_prop3_kernel<<<nb(cN0), 256, 0, stream>>>(seg_off(0), seg_src(0), seg_w(0),
      Tbuf0, 18, 9, Tbuf0, 12, Tbuf0, 6, 2.f, cN0);
  csr_prop3_kernel<<<nb(cN0), 256, 0, stream>>>(seg_off(0), seg_src(0), seg_w(0),
      Tbuf0, 18, 12, Tbuf0, 15, Tbuf0, 9, 2.f, cN0);
  gemm18_kernel<<<nb((long long)cN0 * 32), 256, 0, stream>>>(Tbuf0, W0, b0, out0, cN0);

  // pool0: out0 [N0,128] -> Tlvl1 block 0
  csr_prop128_kernel<<<nb((long long)cN1 * 128), 256, 0, stream>>>(
      seg_off(3), seg_src(3), seg_w(3), out0, Tlvl1, nullptr, 1.f, cN1);

  // ================= Level 1 =================
  {
    float* T0 = Tlvl1;
    auto Tk = [&](int k) { return Tlvl1 + (size_t)k * cN1 * 128; };
    auto prop = [&](const float* hin, float* yout, const float* prev, float scale) {
      csr_prop128_kernel<<<nb((long long)cN1 * 128), 256, 0, stream>>>(
          seg_off(1), seg_src(1), seg_w(1), hin, yout, prev, scale, cN1);
    };
    prop(T0, Tk(1), nullptr, 1.f);
    prop(Tk(1), Tk(2), Tk(0), 2.f);
    prop(Tk(2), Tk(3), Tk(1), 2.f);
    prop(Tk(3), Tk(4), Tk(2), 2.f);
    prop(Tk(4), Tk(5), Tk(3), 2.f);
    dim3 g((cN1 + 127) / 128, 1);
    gemm_fused_kernel<<<g, 256, 0, stream>>>(Tlvl1, W1, b1, out1, cN1, 128, 1);
  }

  // pool1: out1 [N1,128] -> Tlvl2 block 0
  csr_prop128_kernel<<<nb((long long)cN2 * 128), 256, 0, stream>>>(
      seg_off(4), seg_src(4), seg_w(4), out1, Tlvl2, nullptr, 1.f, cN2);

  // ================= Level 2 (no relu, N=256) =================
  {
    auto Tk = [&](int k) { return Tlvl2 + (size_t)k * cN2 * 128; };
    auto prop = [&](const float* hin, float* yout, const float* prev, float scale) {
      csr_prop128_kernel<<<nb((long long)cN2 * 128), 256, 0, stream>>>(
          seg_off(2), seg_src(2), seg_w(2), hin, yout, prev, scale, cN2);
    };
    prop(Tk(0), Tk(1), nullptr, 1.f);
    prop(Tk(1), Tk(2), Tk(0), 2.f);
    prop(Tk(2), Tk(3), Tk(1), 2.f);
    prop(Tk(3), Tk(4), Tk(2), 2.f);
    prop(Tk(4), Tk(5), Tk(3), 2.f);
    dim3 g((cN2 + 127) / 128, 2);
    gemm_fused_kernel<<<g, 256, 0, stream>>>(Tlvl2, W2, b2, out2, cN2, 256, 0);
  }

  // ---- linear head ----
  initout_kernel<<<1, 64, 0, stream>>>(out, linb);
  linear_kernel<<<512, 256, 0, stream>>>(linW, out2, out, cD);
}

// Round 4
// 727.119 us; speedup vs baseline: 1.7865x; 1.1974x over previous
//
#include <hip/hip_runtime.h>

// ChebClassifier R4: bf16 MFMA GEMM (16x16x32) for the K=768 fused level
// GEMMs, 64x64 tiles / 4 waves / 32x32 per wave, fp32->bf16 convert in LDS
// staging (props & recurrence stay fp32). W pre-transposed to bf16 once.

namespace {
constexpr int cN0 = 100000, cN1 = 25000, cN2 = 6250;
constexpr int cE0 = 600000, cE1 = 150000, cE2 = 37500;
constexpr int cP0 = 100000, cP1 = 25000;
constexpr int cD  = cN2 * 256;

constexpr int SEG_N[5]     = {cN0, cN1, cN2, cN1, cN2};
constexpr int NBASE[5]     = {0, 100096, 125184, 131584, 156672};
constexpr int NPAD_TOTAL   = 163072;
constexpr int BLKBASE[5]   = {0, 391, 489, 514, 612};
constexpr int BLK_TOTAL    = 637;
constexpr int EBASE[5]     = {0, 600000, 750000, 787500, 887500};
constexpr int E_TOTAL      = 912500;
constexpr int DEGBASE[5]   = {0, 100000, 125000, 0, 0};
constexpr int DEG_TOTAL    = 131250;
}

typedef __attribute__((ext_vector_type(8))) short short8;
typedef __attribute__((ext_vector_type(4))) float floatx4;

__device__ inline ushort f2bf(float f) {
  union { float f; unsigned u; } v; v.f = f;
  unsigned u = v.u;
  return (ushort)((u + 0x7FFFu + ((u >> 16) & 1u)) >> 16);
}

// ---------------- batched CSR build ----------------
__global__ void zero_all_kernel(int* __restrict__ cnt, int* __restrict__ deg) {
  int i = blockIdx.x * 256 + threadIdx.x;
  if (i < NPAD_TOTAL) cnt[i] = 0;
  if (i < DEG_TOTAL) deg[i] = 0;
}

__global__ void hist_all_kernel(const int* __restrict__ d0, const int* __restrict__ s0,
                                const int* __restrict__ d1, const int* __restrict__ s1,
                                const int* __restrict__ d2, const int* __restrict__ s2,
                                const int* __restrict__ p0r, const int* __restrict__ p1r,
                                int* __restrict__ cnt, int* __restrict__ deg) {
  int e = blockIdx.x * 256 + threadIdx.x;
  if (e >= E_TOTAL) return;
  int seg = (e < EBASE[1]) ? 0 : (e < EBASE[2]) ? 1 : (e < EBASE[3]) ? 2 : (e < EBASE[4]) ? 3 : 4;
  int le = e - EBASE[seg];
  const int* a; const int* b = nullptr;
  if (seg == 0) { a = d0; b = s0; }
  else if (seg == 1) { a = d1; b = s1; }
  else if (seg == 2) { a = d2; b = s2; }
  else if (seg == 3) { a = p0r; }
  else { a = p1r; }
  atomicAdd(&cnt[NBASE[seg] + a[le]], 1);
  if (seg < 3) atomicAdd(&deg[DEGBASE[seg] + b[le]], 1);
}

__global__ void scan1_all_kernel(const int* __restrict__ cnt, int* __restrict__ off,
                                 int* __restrict__ bsum, const int* __restrict__ deg,
                                 float* __restrict__ dinv) {
  __shared__ int s[256];
  int blk = blockIdx.x;
  int seg = (blk < BLKBASE[1]) ? 0 : (blk < BLKBASE[2]) ? 1 : (blk < BLKBASE[3]) ? 2
          : (blk < BLKBASE[4]) ? 3 : 4;
  int j = (blk - BLKBASE[seg]) * 256 + threadIdx.x;
  int N = SEG_N[seg];
  int v = (j < N) ? cnt[NBASE[seg] + j] : 0;
  s[threadIdx.x] = v;
  __syncthreads();
  for (int d = 1; d < 256; d <<= 1) {
    int t = (threadIdx.x >= d) ? s[threadIdx.x - d] : 0;
    __syncthreads();
    s[threadIdx.x] += t;
    __syncthreads();
  }
  off[NBASE[seg] + j] = s[threadIdx.x] - v;
  if (threadIdx.x == 255) bsum[blk] = s[255];
  if (seg < 3 && j < N) {
    int dg = deg[DEGBASE[seg] + j];
    dinv[DEGBASE[seg] + j] = (dg > 0) ? rsqrtf((float)dg) : 0.f;
  }
}

__global__ void scan2_all_kernel(const int* __restrict__ bsum, int* __restrict__ boff) {
  __shared__ int s[512];
  int seg = blockIdx.x;
  int nB = ((seg == 4) ? BLK_TOTAL : BLKBASE[seg + 1]) - BLKBASE[seg];
  int v = (threadIdx.x < nB) ? bsum[BLKBASE[seg] + threadIdx.x] : 0;
  s[threadIdx.x] = v;
  __syncthreads();
  for (int d = 1; d < 512; d <<= 1) {
    int t = (threadIdx.x >= d) ? s[threadIdx.x - d] : 0;
    __syncthreads();
    s[threadIdx.x] += t;
    __syncthreads();
  }
  if (threadIdx.x < nB) boff[BLKBASE[seg] + threadIdx.x] = s[threadIdx.x] - v;
}

__global__ void addoff_all_kernel(int* __restrict__ off, const int* __restrict__ boff,
                                  int* __restrict__ cursor) {
  int blk = blockIdx.x;
  int seg = (blk < BLKBASE[1]) ? 0 : (blk < BLKBASE[2]) ? 1 : (blk < BLKBASE[3]) ? 2
          : (blk < BLKBASE[4]) ? 3 : 4;
  int j = (blk - BLKBASE[seg]) * 256 + threadIdx.x;
  int i = NBASE[seg] + j;
  int v = off[i] + boff[blk];
  off[i] = v;
  cursor[i] = v;
}

__global__ void scatter_all_kernel(const int* __restrict__ d0, const int* __restrict__ s0,
                                   const int* __restrict__ d1, const int* __restrict__ s1,
                                   const int* __restrict__ d2, const int* __restrict__ s2,
                                   const int* __restrict__ p0r, const int* __restrict__ p0c,
                                   const float* __restrict__ p0v,
                                   const int* __restrict__ p1r, const int* __restrict__ p1c,
                                   const float* __restrict__ p1v,
                                   const float* __restrict__ dinv,
                                   int* __restrict__ cursor, int* __restrict__ csrc,
                                   float* __restrict__ cw) {
  int e = blockIdx.x * 256 + threadIdx.x;
  if (e >= E_TOTAL) return;
  int seg = (e < EBASE[1]) ? 0 : (e < EBASE[2]) ? 1 : (e < EBASE[3]) ? 2 : (e < EBASE[4]) ? 3 : 4;
  int le = e - EBASE[seg];
  const int* a; const int* b; const float* vv = nullptr;
  if (seg == 0) { a = d0; b = s0; }
  else if (seg == 1) { a = d1; b = s1; }
  else if (seg == 2) { a = d2; b = s2; }
  else if (seg == 3) { a = p0r; b = p0c; vv = p0v; }
  else { a = p1r; b = p1c; vv = p1v; }
  int d = a[le], s = b[le];
  int pos = atomicAdd(&cursor[NBASE[seg] + d], 1);
  float w;
  if (seg < 3) w = -(dinv[DEGBASE[seg] + s] * dinv[DEGBASE[seg] + d]);
  else w = vv[le];
  csrc[EBASE[seg] + pos] = s;
  cw[EBASE[seg] + pos] = w;
}

// ---------------- props ----------------
__global__ __launch_bounds__(256) void csr_prop128_kernel(
    const int* __restrict__ off, const int* __restrict__ csrc, const float* __restrict__ cw,
    const float* __restrict__ h, float* __restrict__ y,
    const float* __restrict__ prev, float scale, int N) {
  int r = blockIdx.x * 2 + (threadIdx.x >> 7);
  int f = threadIdx.x & 127;
  if (r >= N) return;
  int s = off[r], e = off[r + 1];
  float acc = 0.f;
  for (int j = s; j < e; ++j)
    acc += cw[j] * h[(size_t)csrc[j] * 128 + f];
  float v = scale * acc;
  if (prev) v -= prev[(size_t)r * 128 + f];
  y[(size_t)r * 128 + f] = v;
}

__global__ void csr_prop3_kernel(const int* __restrict__ off, const int* __restrict__ csrc,
                                 const float* __restrict__ cw,
                                 const float* __restrict__ h, int hs, int ho,
                                 float* __restrict__ y, int yo,
                                 const float* __restrict__ prev, int po,
                                 float scale, int N) {
  int r = blockIdx.x * blockDim.x + threadIdx.x;
  if (r >= N) return;
  int s = off[r], e = off[r + 1];
  float a0 = 0.f, a1 = 0.f, a2 = 0.f;
  for (int j = s; j < e; ++j) {
    float w = cw[j];
    const float* hp = h + (size_t)csrc[j] * hs + ho;
    a0 += w * hp[0]; a1 += w * hp[1]; a2 += w * hp[2];
  }
  a0 *= scale; a1 *= scale; a2 *= scale;
  if (prev) {
    const float* pp = prev + (size_t)r * 18 + po;
    a0 -= pp[0]; a1 -= pp[1]; a2 -= pp[2];
  }
  float* yp = y + (size_t)r * 18 + yo;
  yp[0] = a0; yp[1] = a1; yp[2] = a2;
}

__global__ void copyx_kernel(const float* __restrict__ x, float* __restrict__ Tb, int n3) {
  int i = blockIdx.x * blockDim.x + threadIdx.x;
  if (i < n3) {
    int r = i / 3, c = i - r * 3;
    Tb[(size_t)r * 18 + c] = x[i];
  }
}

// ---------------- GEMMs ----------------
__global__ __launch_bounds__(256) void gemm18_kernel(
    const float* __restrict__ Tb, const float* __restrict__ W,
    const float* __restrict__ bias, float* __restrict__ C, int M) {
  __shared__ float Wl[18 * 128];
  for (int i = threadIdx.x; i < 18 * 128; i += 256) Wl[i] = W[i];
  __syncthreads();
  int idx = blockIdx.x * 256 + threadIdx.x;
  int r = idx >> 5;
  int c4 = (idx & 31) << 2;
  if (r >= M) return;
  const float* a = Tb + (size_t)r * 18;
  float4 acc = *(const float4*)(bias + c4);
#pragma unroll
  for (int t = 0; t < 18; ++t) {
    float av = a[t];
    float4 wv = *(const float4*)&Wl[t * 128 + c4];
    acc.x += av * wv.x; acc.y += av * wv.y;
    acc.z += av * wv.z; acc.w += av * wv.w;
  }
  acc.x = fmaxf(acc.x, 0.f); acc.y = fmaxf(acc.y, 0.f);
  acc.z = fmaxf(acc.z, 0.f); acc.w = fmaxf(acc.w, 0.f);
  *(float4*)(C + (size_t)r * 128 + c4) = acc;
}

// W[768][N] fp32 -> Wt[N][768] bf16
__global__ void prep_w_kernel(const float* __restrict__ W, ushort* __restrict__ Wt, int N) {
  int i = blockIdx.x * 256 + threadIdx.x;
  if (i >= 768 * N) return;
  int k = i / N, n = i - k * N;
  Wt[(size_t)n * 768 + k] = f2bf(W[i]);
}

// C[M,N] = act(bias + T[6][M][128] @ W[768,N]) via bf16 MFMA.
// 64x64 tile, 4 waves, 32x32 per wave (2x2 frags of 16x16x32).
template <int RELU>
__global__ __launch_bounds__(256, 4) void gemm_mfma_kernel(
    const float* __restrict__ T, const ushort* __restrict__ Wt,
    const float* __restrict__ bias, float* __restrict__ C, int M, int N) {
  __shared__ ushort Al[64][40];  // row stride 80 B -> uniform bank spread
  __shared__ ushort Bl[64][40];
  const int tid = threadIdx.x;
  const int rowBase = blockIdx.x * 64;
  const int colBase = blockIdx.y * 64;
  const int wave = tid >> 6;
  const int lane = tid & 63;
  const int m16 = lane & 15;
  const int quad = lane >> 4;
  const int mbase = (wave & 1) * 32;
  const int nbase = (wave >> 1) * 32;
  const size_t Mstride = (size_t)M * 128;

  floatx4 acc[2][2];
#pragma unroll
  for (int i = 0; i < 2; ++i)
#pragma unroll
    for (int j = 0; j < 2; ++j)
#pragma unroll
      for (int r = 0; r < 4; ++r) acc[i][j][r] = 0.f;

  const int sRow = tid >> 2;       // 0..63
  const int sK8 = (tid & 3) * 8;   // 0,8,16,24
  const int growA = rowBase + sRow;
  const bool aValid = growA < M;
  const ushort* wtp = Wt + (size_t)(colBase + sRow) * 768 + sK8;

  for (int kc = 0; kc < 24; ++kc) {
    // ---- stage A (fp32 -> bf16) ----
    unsigned p0 = 0, p1 = 0, p2 = 0, p3 = 0;
    if (aValid) {
      const float* ap = T + (size_t)(kc >> 2) * Mstride + (size_t)growA * 128
                        + ((kc & 3) << 5) + sK8;
      float4 v0 = *(const float4*)ap;
      float4 v1 = *(const float4*)(ap + 4);
      p0 = f2bf(v0.x) | ((unsigned)f2bf(v0.y) << 16);
      p1 = f2bf(v0.z) | ((unsigned)f2bf(v0.w) << 16);
      p2 = f2bf(v1.x) | ((unsigned)f2bf(v1.y) << 16);
      p3 = f2bf(v1.z) | ((unsigned)f2bf(v1.w) << 16);
    }
    *(uint4*)&Al[sRow][sK8] = make_uint4(p0, p1, p2, p3);
    // ---- stage B (already bf16, [N][768]) ----
    *(uint4*)&Bl[sRow][sK8] = *(const uint4*)(wtp + kc * 32);
    __syncthreads();

    short8 a0 = *(const short8*)&Al[mbase + m16][quad * 8];
    short8 a1 = *(const short8*)&Al[mbase + 16 + m16][quad * 8];
    short8 b0 = *(const short8*)&Bl[nbase + m16][quad * 8];
    short8 b1 = *(const short8*)&Bl[nbase + 16 + m16][quad * 8];
    acc[0][0] = __builtin_amdgcn_mfma_f32_16x16x32_bf16(a0, b0, acc[0][0], 0, 0, 0);
    acc[0][1] = __builtin_amdgcn_mfma_f32_16x16x32_bf16(a0, b1, acc[0][1], 0, 0, 0);
    acc[1][0] = __builtin_amdgcn_mfma_f32_16x16x32_bf16(a1, b0, acc[1][0], 0, 0, 0);
    acc[1][1] = __builtin_amdgcn_mfma_f32_16x16x32_bf16(a1, b1, acc[1][1], 0, 0, 0);
    __syncthreads();
  }

#pragma unroll
  for (int ni = 0; ni < 2; ++ni) {
    int col = colBase + nbase + ni * 16 + m16;
    float bv = bias[col];
#pragma unroll
    for (int mi = 0; mi < 2; ++mi) {
#pragma unroll
      for (int r = 0; r < 4; ++r) {
        int row = rowBase + mbase + mi * 16 + quad * 4 + r;
        if (row < M) {
          float v = acc[mi][ni][r] + bv;
          if (RELU) v = fmaxf(v, 0.f);
          C[(size_t)row * N + col] = v;
        }
      }
    }
  }
}

// ---------------- linear head ----------------
__global__ void initout_kernel(float* __restrict__ out, const float* __restrict__ linb) {
  int i = threadIdx.x;
  if (i < 10) out[i] = linb[i];
}

__global__ __launch_bounds__(256) void linear_kernel(const float* __restrict__ Wl,
                                                     const float* __restrict__ h,
                                                     float* __restrict__ out, int D) {
  float p[10];
#pragma unroll
  for (int j = 0; j < 10; ++j) p[j] = 0.f;
  int stride = gridDim.x * blockDim.x;
  for (int i = blockIdx.x * blockDim.x + threadIdx.x; i < D; i += stride) {
    float hv = h[i];
#pragma unroll
    for (int j = 0; j < 10; ++j) p[j] += Wl[(size_t)j * D + i] * hv;
  }
#pragma unroll
  for (int j = 0; j < 10; ++j) {
#pragma unroll
    for (int off = 32; off > 0; off >>= 1) p[j] += __shfl_down(p[j], off, 64);
  }
  __shared__ float s[4][10];
  int wave = threadIdx.x >> 6, lane = threadIdx.x & 63;
  if (lane == 0) {
#pragma unroll
    for (int j = 0; j < 10; ++j) s[wave][j] = p[j];
  }
  __syncthreads();
  if (threadIdx.x < 10) {
    float t = s[0][threadIdx.x] + s[1][threadIdx.x] + s[2][threadIdx.x] + s[3][threadIdx.x];
    atomicAdd(&out[threadIdx.x], t);
  }
}

// ---------------- host orchestration ----------------
extern "C" void kernel_launch(void* const* d_in, const int* in_sizes, int n_in,
                              void* d_out, int out_size, void* d_ws, size_t ws_size,
                              hipStream_t stream) {
  const float* x    = (const float*)d_in[0];
  const int*   ei0  = (const int*)d_in[1];
  const int*   ei1  = (const int*)d_in[2];
  const int*   ei2  = (const int*)d_in[3];
  const float* W0   = (const float*)d_in[4];
  const float* b0   = (const float*)d_in[5];
  const float* W1   = (const float*)d_in[6];
  const float* b1   = (const float*)d_in[7];
  const float* W2   = (const float*)d_in[8];
  const float* b2   = (const float*)d_in[9];
  const int*   D0r  = (const int*)d_in[10];
  const int*   D0c  = (const int*)d_in[11];
  const float* D0v  = (const float*)d_in[12];
  const int*   D1r  = (const int*)d_in[13];
  const int*   D1c  = (const int*)d_in[14];
  const float* D1v  = (const float*)d_in[15];
  const float* linW = (const float*)d_in[16];
  const float* linb = (const float*)d_in[17];
  float* out = (float*)d_out;
  (void)in_sizes; (void)n_in; (void)out_size; (void)ws_size;

  const int* src0 = ei0;            const int* dst0 = ei0 + cE0;
  const int* src1 = ei1;            const int* dst1 = ei1 + cE1;
  const int* src2 = ei2;            const int* dst2 = ei2 + cE2;

  float* ws = (float*)d_ws;
  size_t off = 0;
  auto alloc = [&](size_t n) {
    float* p = ws + off;
    off += (n + 63) & ~size_t(63);
    return p;
  };
  int*   deg     = (int*)alloc(DEG_TOTAL);
  float* dinv    = alloc(DEG_TOTAL);
  int*   cnt     = (int*)alloc(NPAD_TOTAL);
  int*   offArr  = (int*)alloc(NPAD_TOTAL);
  int*   cursor  = (int*)alloc(NPAD_TOTAL);
  int*   bsum    = (int*)alloc(BLK_TOTAL);
  int*   boff    = (int*)alloc(BLK_TOTAL);
  int*   csrX    = (int*)alloc(E_TOTAL);
  float* csrW    = alloc(E_TOTAL);
  ushort* Wt1    = (ushort*)alloc(768 * 128 / 2);
  ushort* Wt2    = (ushort*)alloc(768 * 256 / 2);
  float* Tbuf0   = alloc((size_t)cN0 * 18);
  float* out0    = alloc((size_t)cN0 * 128);
  float* Tlvl1   = alloc((size_t)6 * cN1 * 128);
  float* out1    = alloc((size_t)cN1 * 128);
  float* Tlvl2   = alloc((size_t)6 * cN2 * 128);
  float* out2    = alloc((size_t)cN2 * 256);

  auto nb = [](long long n) { return (unsigned)((n + 255) / 256); };

  // ---- batched CSR build ----
  zero_all_kernel<<<nb(NPAD_TOTAL), 256, 0, stream>>>(cnt, deg);
  hist_all_kernel<<<nb(E_TOTAL), 256, 0, stream>>>(dst0, src0, dst1, src1, dst2, src2,
                                                   D0r, D1r, cnt, deg);
  scan1_all_kernel<<<BLK_TOTAL, 256, 0, stream>>>(cnt, offArr, bsum, deg, dinv);
  scan2_all_kernel<<<5, 512, 0, stream>>>(bsum, boff);
  addoff_all_kernel<<<BLK_TOTAL, 256, 0, stream>>>(offArr, boff, cursor);
  scatter_all_kernel<<<nb(E_TOTAL), 256, 0, stream>>>(dst0, src0, dst1, src1, dst2, src2,
                                                      D0r, D0c, D0v, D1r, D1c, D1v,
                                                      dinv, cursor, csrX, csrW);
  // ---- weight prep (bf16 transposed) ----
  prep_w_kernel<<<nb(768 * 128), 256, 0, stream>>>(W1, Wt1, 128);
  prep_w_kernel<<<nb(768 * 256), 256, 0, stream>>>(W2, Wt2, 256);

  auto seg_off  = [&](int s) { return offArr + NBASE[s]; };
  auto seg_src  = [&](int s) { return csrX + EBASE[s]; };
  auto seg_w    = [&](int s) { return csrW + EBASE[s]; };

  // ================= Level 0 (F=3 -> 128) =================
  copyx_kernel<<<nb((long long)cN0 * 3), 256, 0, stream>>>(x, Tbuf0, cN0 * 3);
  csr_prop3_kernel<<<nb(cN0), 256, 0, stream>>>(seg_off(0), seg_src(0), seg_w(0),
      x, 3, 0, Tbuf0, 3, nullptr, 0, 1.f, cN0);
  csr_prop3_kernel<<<nb(cN0), 256, 0, stream>>>(seg_off(0), seg_src(0), seg_w(0),
      Tbuf0, 18, 3, Tbuf0, 6, Tbuf0, 0, 2.f, cN0);
  csr_prop3_kernel<<<nb(cN0), 256, 0, stream>>>(seg_off(0), seg_src(0), seg_w(0),
      Tbuf0, 18, 6, Tbuf0, 9, Tbuf0, 3, 2.f, cN0);
  csr_prop3_kernel<<<nb(cN0), 256, 0, stream>>>(seg_off(0), seg_src(0), seg_w(0),
      Tbuf0, 18, 9, Tbuf0, 12, Tbuf0, 6, 2.f, cN0);
  csr_prop3_kernel<<<nb(cN0), 256, 0, stream>>>(seg_off(0), seg_src(0), seg_w(0),
      Tbuf0, 18, 12, Tbuf0, 15, Tbuf0, 9, 2.f, cN0);
  gemm18_kernel<<<nb((long long)cN0 * 32), 256, 0, stream>>>(Tbuf0, W0, b0, out0, cN0);

  // pool0 -> Tlvl1 block 0
  csr_prop128_kernel<<<nb((long long)cN1 * 128), 256, 0, stream>>>(
      seg_off(3), seg_src(3), seg_w(3), out0, Tlvl1, nullptr, 1.f, cN1);

  // ================= Level 1 =================
  {
    auto Tk = [&](int k) { return Tlvl1 + (size_t)k * cN1 * 128; };
    auto prop = [&](const float* hin, float* yout, const float* prev, float scale) {
      csr_prop128_kernel<<<nb((long long)cN1 * 128), 256, 0, stream>>>(
          seg_off(1), seg_src(1), seg_w(1), hin, yout, prev, scale, cN1);
    };
    prop(Tk(0), Tk(1), nullptr, 1.f);
    prop(Tk(1), Tk(2), Tk(0), 2.f);
    prop(Tk(2), Tk(3), Tk(1), 2.f);
    prop(Tk(3), Tk(4), Tk(2), 2.f);
    prop(Tk(4), Tk(5), Tk(3), 2.f);
    dim3 g((cN1 + 63) / 64, 2);
    gemm_mfma_kernel<1><<<g, 256, 0, stream>>>(Tlvl1, Wt1, b1, out1, cN1, 128);
  }

  // pool1 -> Tlvl2 block 0
  csr_prop128_kernel<<<nb((long long)cN2 * 128), 256, 0, stream>>>(
      seg_off(4), seg_src(4), seg_w(4), out1, Tlvl2, nullptr, 1.f, cN2);

  // ================= Level 2 (no relu, N=256) =================
  {
    auto Tk = [&](int k) { return Tlvl2 + (size_t)k * cN2 * 128; };
    auto prop = [&](const float* hin, float* yout, const float* prev, float scale) {
      csr_prop128_kernel<<<nb((long long)cN2 * 128), 256, 0, stream>>>(
          seg_off(2), seg_src(2), seg_w(2), hin, yout, prev, scale, cN2);
    };
    prop(Tk(0), Tk(1), nullptr, 1.f);
    prop(Tk(1), Tk(2), Tk(0), 2.f);
    prop(Tk(2), Tk(3), Tk(1), 2.f);
    prop(Tk(3), Tk(4), Tk(2), 2.f);
    prop(Tk(4), Tk(5), Tk(3), 2.f);
    dim3 g((cN2 + 63) / 64, 4);
    gemm_mfma_kernel<0><<<g, 256, 0, stream>>>(Tlvl2, Wt2, b2, out2, cN2, 256);
  }

  // ---- linear head ----
  initout_kernel<<<1, 64, 0, stream>>>(out, linb);
  linear_kernel<<<512, 256, 0, stream>>>(linW, out2, out, cD);
}

// Round 5
// 693.908 us; speedup vs baseline: 1.8720x; 1.0479x over previous
//
#include <hip/hip_runtime.h>

// ChebClassifier R5: rank-trick CSR build (scatter is atomic-free), (src,w)
// interleaved as int2 pairs (1 dirty line per edge), 64x128 MFMA GEMM tile
// (A read once for L1). Props/recurrence stay fp32.

namespace {
constexpr int cN0 = 100000, cN1 = 25000, cN2 = 6250;
constexpr int cE0 = 600000, cE1 = 150000, cE2 = 37500;
constexpr int cD  = cN2 * 256;

constexpr int SEG_N[5]     = {cN0, cN1, cN2, cN1, cN2};
constexpr int NBASE[5]     = {0, 100096, 125184, 131584, 156672};
constexpr int NPAD_TOTAL   = 163072;
constexpr int BLKBASE[5]   = {0, 391, 489, 514, 612};
constexpr int BLK_TOTAL    = 637;
constexpr int EBASE[5]     = {0, 600000, 750000, 787500, 887500};
constexpr int E_TOTAL      = 912500;
constexpr int DEGBASE[5]   = {0, 100000, 125000, 0, 0};
constexpr int DEG_TOTAL    = 131250;
}

typedef __attribute__((ext_vector_type(8))) short short8;
typedef __attribute__((ext_vector_type(4))) float floatx4;

__device__ inline ushort f2bf(float f) {
  union { float f; unsigned u; } v; v.f = f;
  unsigned u = v.u;
  return (ushort)((u + 0x7FFFu + ((u >> 16) & 1u)) >> 16);
}

// ---------------- batched CSR build ----------------
__global__ void zero_all_kernel(int* __restrict__ cnt, int* __restrict__ deg) {
  int i = blockIdx.x * 256 + threadIdx.x;
  if (i < NPAD_TOTAL) cnt[i] = 0;
  if (i < DEG_TOTAL) deg[i] = 0;
}

// histogram + per-edge rank (rank trick) + deg histogram for graph segs
__global__ void hist_all_kernel(const int* __restrict__ d0, const int* __restrict__ s0,
                                const int* __restrict__ d1, const int* __restrict__ s1,
                                const int* __restrict__ d2, const int* __restrict__ s2,
                                const int* __restrict__ p0r, const int* __restrict__ p1r,
                                int* __restrict__ cnt, int* __restrict__ deg,
                                int* __restrict__ rank) {
  int e = blockIdx.x * 256 + threadIdx.x;
  if (e >= E_TOTAL) return;
  int seg = (e < EBASE[1]) ? 0 : (e < EBASE[2]) ? 1 : (e < EBASE[3]) ? 2 : (e < EBASE[4]) ? 3 : 4;
  int le = e - EBASE[seg];
  const int* a; const int* b = nullptr;
  if (seg == 0) { a = d0; b = s0; }
  else if (seg == 1) { a = d1; b = s1; }
  else if (seg == 2) { a = d2; b = s2; }
  else if (seg == 3) { a = p0r; }
  else { a = p1r; }
  rank[e] = atomicAdd(&cnt[NBASE[seg] + a[le]], 1);
  if (seg < 3) atomicAdd(&deg[DEGBASE[seg] + b[le]], 1);
}

__global__ void scan1_all_kernel(const int* __restrict__ cnt, int* __restrict__ off,
                                 int* __restrict__ bsum, const int* __restrict__ deg,
                                 float* __restrict__ dinv) {
  __shared__ int s[256];
  int blk = blockIdx.x;
  int seg = (blk < BLKBASE[1]) ? 0 : (blk < BLKBASE[2]) ? 1 : (blk < BLKBASE[3]) ? 2
          : (blk < BLKBASE[4]) ? 3 : 4;
  int j = (blk - BLKBASE[seg]) * 256 + threadIdx.x;
  int N = SEG_N[seg];
  int v = (j < N) ? cnt[NBASE[seg] + j] : 0;
  s[threadIdx.x] = v;
  __syncthreads();
  for (int d = 1; d < 256; d <<= 1) {
    int t = (threadIdx.x >= d) ? s[threadIdx.x - d] : 0;
    __syncthreads();
    s[threadIdx.x] += t;
    __syncthreads();
  }
  off[NBASE[seg] + j] = s[threadIdx.x] - v;
  if (threadIdx.x == 255) bsum[blk] = s[255];
  if (seg < 3 && j < N) {
    int dg = deg[DEGBASE[seg] + j];
    dinv[DEGBASE[seg] + j] = (dg > 0) ? rsqrtf((float)dg) : 0.f;
  }
}

__global__ void scan2_all_kernel(const int* __restrict__ bsum, int* __restrict__ boff) {
  __shared__ int s[512];
  int seg = blockIdx.x;
  int nB = ((seg == 4) ? BLK_TOTAL : BLKBASE[seg + 1]) - BLKBASE[seg];
  int v = (threadIdx.x < nB) ? bsum[BLKBASE[seg] + threadIdx.x] : 0;
  s[threadIdx.x] = v;
  __syncthreads();
  for (int d = 1; d < 512; d <<= 1) {
    int t = (threadIdx.x >= d) ? s[threadIdx.x - d] : 0;
    __syncthreads();
    s[threadIdx.x] += t;
    __syncthreads();
  }
  if (threadIdx.x < nB) boff[BLKBASE[seg] + threadIdx.x] = s[threadIdx.x] - v;
}

__global__ void addoff_all_kernel(int* __restrict__ off, const int* __restrict__ boff) {
  int blk = blockIdx.x;
  int i = blk * 256 + threadIdx.x;  // NBASE layout is contiguous in block space
  off[i] += boff[blk];
}

// atomic-free scatter: pos = off[key] + rank[e]; write interleaved (src, w)
__global__ void scatter_all_kernel(const int* __restrict__ d0, const int* __restrict__ s0,
                                   const int* __restrict__ d1, const int* __restrict__ s1,
                                   const int* __restrict__ d2, const int* __restrict__ s2,
                                   const int* __restrict__ p0r, const int* __restrict__ p0c,
                                   const float* __restrict__ p0v,
                                   const int* __restrict__ p1r, const int* __restrict__ p1c,
                                   const float* __restrict__ p1v,
                                   const float* __restrict__ dinv,
                                   const int* __restrict__ off, const int* __restrict__ rank,
                                   int2* __restrict__ pairs) {
  int e = blockIdx.x * 256 + threadIdx.x;
  if (e >= E_TOTAL) return;
  int seg = (e < EBASE[1]) ? 0 : (e < EBASE[2]) ? 1 : (e < EBASE[3]) ? 2 : (e < EBASE[4]) ? 3 : 4;
  int le = e - EBASE[seg];
  const int* a; const int* b; const float* vv = nullptr;
  if (seg == 0) { a = d0; b = s0; }
  else if (seg == 1) { a = d1; b = s1; }
  else if (seg == 2) { a = d2; b = s2; }
  else if (seg == 3) { a = p0r; b = p0c; vv = p0v; }
  else { a = p1r; b = p1c; vv = p1v; }
  int d = a[le], s = b[le];
  int pos = off[NBASE[seg] + d] + rank[e];
  float w;
  if (seg < 3) w = -(dinv[DEGBASE[seg] + s] * dinv[DEGBASE[seg] + d]);
  else w = vv[le];
  pairs[EBASE[seg] + pos] = make_int2(s, __float_as_int(w));
}

// ---------------- props ----------------
__global__ __launch_bounds__(256) void csr_prop128_kernel(
    const int* __restrict__ off, const int2* __restrict__ pairs,
    const float* __restrict__ h, float* __restrict__ y,
    const float* __restrict__ prev, float scale, int N) {
  int r = blockIdx.x * 2 + (threadIdx.x >> 7);
  int f = threadIdx.x & 127;
  if (r >= N) return;
  int s = off[r], e = off[r + 1];
  float acc = 0.f;
  for (int j = s; j < e; ++j) {
    int2 p = pairs[j];
    acc += __int_as_float(p.y) * h[(size_t)p.x * 128 + f];
  }
  float v = scale * acc;
  if (prev) v -= prev[(size_t)r * 128 + f];
  y[(size_t)r * 128 + f] = v;
}

__global__ void csr_prop3_kernel(const int* __restrict__ off, const int2* __restrict__ pairs,
                                 const float* __restrict__ h, int hs, int ho,
                                 float* __restrict__ y, int yo,
                                 const float* __restrict__ prev, int po,
                                 float scale, int N) {
  int r = blockIdx.x * blockDim.x + threadIdx.x;
  if (r >= N) return;
  int s = off[r], e = off[r + 1];
  float a0 = 0.f, a1 = 0.f, a2 = 0.f;
  for (int j = s; j < e; ++j) {
    int2 p = pairs[j];
    float w = __int_as_float(p.y);
    const float* hp = h + (size_t)p.x * hs + ho;
    a0 += w * hp[0]; a1 += w * hp[1]; a2 += w * hp[2];
  }
  a0 *= scale; a1 *= scale; a2 *= scale;
  if (prev) {
    const float* pp = prev + (size_t)r * 18 + po;
    a0 -= pp[0]; a1 -= pp[1]; a2 -= pp[2];
  }
  float* yp = y + (size_t)r * 18 + yo;
  yp[0] = a0; yp[1] = a1; yp[2] = a2;
}

__global__ void copyx_kernel(const float* __restrict__ x, float* __restrict__ Tb, int n3) {
  int i = blockIdx.x * blockDim.x + threadIdx.x;
  if (i < n3) {
    int r = i / 3, c = i - r * 3;
    Tb[(size_t)r * 18 + c] = x[i];
  }
}

// ---------------- GEMMs ----------------
__global__ __launch_bounds__(256) void gemm18_kernel(
    const float* __restrict__ Tb, const float* __restrict__ W,
    const float* __restrict__ bias, float* __restrict__ C, int M) {
  __shared__ float Wl[18 * 128];
  for (int i = threadIdx.x; i < 18 * 128; i += 256) Wl[i] = W[i];
  __syncthreads();
  int idx = blockIdx.x * 256 + threadIdx.x;
  int r = idx >> 5;
  int c4 = (idx & 31) << 2;
  if (r >= M) return;
  const float* a = Tb + (size_t)r * 18;
  float4 acc = *(const float4*)(bias + c4);
#pragma unroll
  for (int t = 0; t < 18; ++t) {
    float av = a[t];
    float4 wv = *(const float4*)&Wl[t * 128 + c4];
    acc.x += av * wv.x; acc.y += av * wv.y;
    acc.z += av * wv.z; acc.w += av * wv.w;
  }
  acc.x = fmaxf(acc.x, 0.f); acc.y = fmaxf(acc.y, 0.f);
  acc.z = fmaxf(acc.z, 0.f); acc.w = fmaxf(acc.w, 0.f);
  *(float4*)(C + (size_t)r * 128 + c4) = acc;
}

__global__ void prep_w_kernel(const float* __restrict__ W, ushort* __restrict__ Wt, int N) {
  int i = blockIdx.x * 256 + threadIdx.x;
  if (i >= 768 * N) return;
  int k = i / N, n = i - k * N;
  Wt[(size_t)n * 768 + k] = f2bf(W[i]);
}

// C[M,N] = act(bias + T[6][M][128] @ W[768,N]) via bf16 MFMA.
// 64x128 tile, 4 waves; each wave 16 rows x 128 cols (1x8 frags 16x16x32).
template <int RELU>
__global__ __launch_bounds__(256, 2) void gemm_mfma_kernel(
    const float* __restrict__ T, const ushort* __restrict__ Wt,
    const float* __restrict__ bias, float* __restrict__ C, int M, int N) {
  __shared__ ushort Al[64][40];
  __shared__ ushort Bl[128][40];
  const int tid = threadIdx.x;
  const int rowBase = blockIdx.x * 64;
  const int colBase = blockIdx.y * 128;
  const int wave = tid >> 6;
  const int lane = tid & 63;
  const int m16 = lane & 15;
  const int quad = lane >> 4;
  const size_t Mstride = (size_t)M * 128;

  floatx4 acc[8];
#pragma unroll
  for (int c = 0; c < 8; ++c)
#pragma unroll
    for (int r = 0; r < 4; ++r) acc[c][r] = 0.f;

  const int sRow = tid >> 2;       // 0..63
  const int sK8 = (tid & 3) * 8;   // 0,8,16,24
  const int growA = rowBase + sRow;
  const bool aValid = growA < M;

  for (int kc = 0; kc < 24; ++kc) {
    // stage A (fp32 -> bf16), 64 rows x 32 k
    unsigned p0 = 0, p1 = 0, p2 = 0, p3 = 0;
    if (aValid) {
      const float* ap = T + (size_t)(kc >> 2) * Mstride + (size_t)growA * 128
                        + ((kc & 3) << 5) + sK8;
      float4 v0 = *(const float4*)ap;
      float4 v1 = *(const float4*)(ap + 4);
      p0 = f2bf(v0.x) | ((unsigned)f2bf(v0.y) << 16);
      p1 = f2bf(v0.z) | ((unsigned)f2bf(v0.w) << 16);
      p2 = f2bf(v1.x) | ((unsigned)f2bf(v1.y) << 16);
      p3 = f2bf(v1.z) | ((unsigned)f2bf(v1.w) << 16);
    }
    *(uint4*)&Al[sRow][sK8] = make_uint4(p0, p1, p2, p3);
    // stage B, 128 cols x 32 k (Wt is [N][768] bf16)
#pragma unroll
    for (int l = 0; l < 2; ++l) {
      int lin = tid + l * 256;
      int bRow = lin >> 2;
      int bK8 = (lin & 3) * 8;
      *(uint4*)&Bl[bRow][bK8] =
          *(const uint4*)(Wt + (size_t)(colBase + bRow) * 768 + kc * 32 + bK8);
    }
    __syncthreads();

    short8 a = *(const short8*)&Al[wave * 16 + m16][quad * 8];
#pragma unroll
    for (int c = 0; c < 8; ++c) {
      short8 b = *(const short8*)&Bl[c * 16 + m16][quad * 8];
      acc[c] = __builtin_amdgcn_mfma_f32_16x16x32_bf16(a, b, acc[c], 0, 0, 0);
    }
    __syncthreads();
  }

#pragma unroll
  for (int c = 0; c < 8; ++c) {
    int col = colBase + c * 16 + m16;
    float bv = bias[col];
#pragma unroll
    for (int r = 0; r < 4; ++r) {
      int row = rowBase + wave * 16 + quad * 4 + r;
      if (row < M) {
        float v = acc[c][r] + bv;
        if (RELU) v = fmaxf(v, 0.f);
        C[(size_t)row * N + col] = v;
      }
    }
  }
}

// ---------------- linear head ----------------
__global__ void initout_kernel(float* __restrict__ out, const float* __restrict__ linb) {
  int i = threadIdx.x;
  if (i < 10) out[i] = linb[i];
}

__global__ __launch_bounds__(256) void linear_kernel(const float* __restrict__ Wl,
                                                     const float* __restrict__ h,
                                                     float* __restrict__ out, int D) {
  float p[10];
#pragma unroll
  for (int j = 0; j < 10; ++j) p[j] = 0.f;
  int stride = gridDim.x * blockDim.x;
  for (int i = blockIdx.x * blockDim.x + threadIdx.x; i < D; i += stride) {
    float hv = h[i];
#pragma unroll
    for (int j = 0; j < 10; ++j) p[j] += Wl[(size_t)j * D + i] * hv;
  }
#pragma unroll
  for (int j = 0; j < 10; ++j) {
#pragma unroll
    for (int off = 32; off > 0; off >>= 1) p[j] += __shfl_down(p[j], off, 64);
  }
  __shared__ float s[4][10];
  int wave = threadIdx.x >> 6, lane = threadIdx.x & 63;
  if (lane == 0) {
#pragma unroll
    for (int j = 0; j < 10; ++j) s[wave][j] = p[j];
  }
  __syncthreads();
  if (threadIdx.x < 10) {
    float t = s[0][threadIdx.x] + s[1][threadIdx.x] + s[2][threadIdx.x] + s[3][threadIdx.x];
    atomicAdd(&out[threadIdx.x], t);
  }
}

// ---------------- host orchestration ----------------
extern "C" void kernel_launch(void* const* d_in, const int* in_sizes, int n_in,
                              void* d_out, int out_size, void* d_ws, size_t ws_size,
                              hipStream_t stream) {
  const float* x    = (const float*)d_in[0];
  const int*   ei0  = (const int*)d_in[1];
  const int*   ei1  = (const int*)d_in[2];
  const int*   ei2  = (const int*)d_in[3];
  const float* W0   = (const float*)d_in[4];
  const float* b0   = (const float*)d_in[5];
  const float* W1   = (const float*)d_in[6];
  const float* b1   = (const float*)d_in[7];
  const float* W2   = (const float*)d_in[8];
  const float* b2   = (const float*)d_in[9];
  const int*   D0r  = (const int*)d_in[10];
  const int*   D0c  = (const int*)d_in[11];
  const float* D0v  = (const float*)d_in[12];
  const int*   D1r  = (const int*)d_in[13];
  const int*   D1c  = (const int*)d_in[14];
  const float* D1v  = (const float*)d_in[15];
  const float* linW = (const float*)d_in[16];
  const float* linb = (const float*)d_in[17];
  float* out = (float*)d_out;
  (void)in_sizes; (void)n_in; (void)out_size; (void)ws_size;

  const int* src0 = ei0;            const int* dst0 = ei0 + cE0;
  const int* src1 = ei1;            const int* dst1 = ei1 + cE1;
  const int* src2 = ei2;            const int* dst2 = ei2 + cE2;

  float* ws = (float*)d_ws;
  size_t off = 0;
  auto alloc = [&](size_t n) {
    float* p = ws + off;
    off += (n + 63) & ~size_t(63);
    return p;
  };
  int*   deg     = (int*)alloc(DEG_TOTAL);
  float* dinv    = alloc(DEG_TOTAL);
  int*   cnt     = (int*)alloc(NPAD_TOTAL);
  int*   offArr  = (int*)alloc(NPAD_TOTAL);
  int*   rankArr = (int*)alloc(E_TOTAL);
  int*   bsum    = (int*)alloc(BLK_TOTAL);
  int*   boff    = (int*)alloc(BLK_TOTAL);
  int2*  pairs   = (int2*)alloc((size_t)2 * E_TOTAL);
  ushort* Wt1    = (ushort*)alloc(768 * 128 / 2);
  ushort* Wt2    = (ushort*)alloc(768 * 256 / 2);
  float* Tbuf0   = alloc((size_t)cN0 * 18);
  float* out0    = alloc((size_t)cN0 * 128);
  float* Tlvl1   = alloc((size_t)6 * cN1 * 128);
  float* out1    = alloc((size_t)cN1 * 128);
  float* Tlvl2   = alloc((size_t)6 * cN2 * 128);
  float* out2    = alloc((size_t)cN2 * 256);

  auto nb = [](long long n) { return (unsigned)((n + 255) / 256); };

  // ---- batched CSR build (rank trick) ----
  zero_all_kernel<<<nb(NPAD_TOTAL), 256, 0, stream>>>(cnt, deg);
  hist_all_kernel<<<nb(E_TOTAL), 256, 0, stream>>>(dst0, src0, dst1, src1, dst2, src2,
                                                   D0r, D1r, cnt, deg, rankArr);
  scan1_all_kernel<<<BLK_TOTAL, 256, 0, stream>>>(cnt, offArr, bsum, deg, dinv);
  scan2_all_kernel<<<5, 512, 0, stream>>>(bsum, boff);
  addoff_all_kernel<<<BLK_TOTAL, 256, 0, stream>>>(offArr, boff);
  scatter_all_kernel<<<nb(E_TOTAL), 256, 0, stream>>>(dst0, src0, dst1, src1, dst2, src2,
                                                      D0r, D0c, D0v, D1r, D1c, D1v,
                                                      dinv, offArr, rankArr, pairs);
  prep_w_kernel<<<nb(768 * 128), 256, 0, stream>>>(W1, Wt1, 128);
  prep_w_kernel<<<nb(768 * 256), 256, 0, stream>>>(W2, Wt2, 256);

  auto seg_off   = [&](int s) { return offArr + NBASE[s]; };
  auto seg_pairs = [&](int s) { return pairs + EBASE[s]; };

  // ================= Level 0 (F=3 -> 128) =================
  copyx_kernel<<<nb((long long)cN0 * 3), 256, 0, stream>>>(x, Tbuf0, cN0 * 3);
  csr_prop3_kernel<<<nb(cN0), 256, 0, stream>>>(seg_off(0), seg_pairs(0),
      x, 3, 0, Tbuf0, 3, nullptr, 0, 1.f, cN0);
  csr_prop3_kernel<<<nb(cN0), 256, 0, stream>>>(seg_off(0), seg_pairs(0),
      Tbuf0, 18, 3, Tbuf0, 6, Tbuf0, 0, 2.f, cN0);
  csr_prop3_kernel<<<nb(cN0), 256, 0, stream>>>(seg_off(0), seg_pairs(0),
      Tbuf0, 18, 6, Tbuf0, 9, Tbuf0, 3, 2.f, cN0);
  csr_prop3_kernel<<<nb(cN0), 256, 0, stream>>>(seg_off(0), seg_pairs(0),
      Tbuf0, 18, 9, Tbuf0, 12, Tbuf0, 6, 2.f, cN0);
  csr_prop3_kernel<<<nb(cN0), 256, 0, stream>>>(seg_off(0), seg_pairs(0),
      Tbuf0, 18, 12, Tbuf0, 15, Tbuf0, 9, 2.f, cN0);
  gemm18_kernel<<<nb((long long)cN0 * 32), 256, 0, stream>>>(Tbuf0, W0, b0, out0, cN0);

  // pool0 -> Tlvl1 block 0
  csr_prop128_kernel<<<nb((long long)cN1 * 128), 256, 0, stream>>>(
      seg_off(3), seg_pairs(3), out0, Tlvl1, nullptr, 1.f, cN1);

  // ================= Level 1 =================
  {
    auto Tk = [&](int k) { return Tlvl1 + (size_t)k * cN1 * 128; };
    auto prop = [&](const float* hin, float* yout, const float* prev, float scale) {
      csr_prop128_kernel<<<nb((long long)cN1 * 128), 256, 0, stream>>>(
          seg_off(1), seg_pairs(1), hin, yout, prev, scale, cN1);
    };
    prop(Tk(0), Tk(1), nullptr, 1.f);
    prop(Tk(1), Tk(2), Tk(0), 2.f);
    prop(Tk(2), Tk(3), Tk(1), 2.f);
    prop(Tk(3), Tk(4), Tk(2), 2.f);
    prop(Tk(4), Tk(5), Tk(3), 2.f);
    dim3 g((cN1 + 63) / 64, 1);
    gemm_mfma_kernel<1><<<g, 256, 0, stream>>>(Tlvl1, Wt1, b1, out1, cN1, 128);
  }

  // pool1 -> Tlvl2 block 0
  csr_prop128_kernel<<<nb((long long)cN2 * 128), 256, 0, stream>>>(
      seg_off(4), seg_pairs(4), out1, Tlvl2, nullptr, 1.f, cN2);

  // ================= Level 2 (no relu, N=256) =================
  {
    auto Tk = [&](int k) { return Tlvl2 + (size_t)k * cN2 * 128; };
    auto prop = [&](const float* hin, float* yout, const float* prev, float scale) {
      csr_prop128_kernel<<<nb((long long)cN2 * 128), 256, 0, stream>>>(
          seg_off(2), seg_pairs(2), hin, yout, prev, scale, cN2);
    };
    prop(Tk(0), Tk(1), nullptr, 1.f);
    prop(Tk(1), Tk(2), Tk(0), 2.f);
    prop(Tk(2), Tk(3), Tk(1), 2.f);
    prop(Tk(3), Tk(4), Tk(2), 2.f);
    prop(Tk(4), Tk(5), Tk(3), 2.f);
    dim3 g((cN2 + 63) / 64, 2);
    gemm_mfma_kernel<0><<<g, 256, 0, stream>>>(Tlvl2, Wt2, b2, out2, cN2, 256);
  }

  // ---- linear head ----
  initout_kernel<<<1, 64, 0, stream>>>(out, linb);
  linear_kernel<<<512, 256, 0, stream>>>(linW, out2, out, cD);
}

// Round 6
// 647.173 us; speedup vs baseline: 2.0072x; 1.0722x over previous
//
#include <hip/hip_runtime.h>

// ChebClassifier R6: fully atomic-free CSR build (coarse-bucket radix:
// LDS chunk histograms -> scans -> bucket scatter -> per-bucket LDS
// finalize producing exact CSR + dinv). Props/GEMMs unchanged from R5.

namespace {
constexpr int cN0 = 100000, cN1 = 25000, cN2 = 6250;
constexpr int cE0 = 600000, cE1 = 150000, cE2 = 37500;
constexpr int cD  = cN2 * 256;

// jobs 0-4: dst-side CSR (graph0/1/2, pool0, pool1); jobs 5-7: src-side deg
constexpr int JN[8]  = {cN0, cN1, cN2, cN1, cN2, cN0, cN1, cN2};
constexpr int JE[8]  = {cE0, cE1, cE2, 100000, 25000, cE0, cE1, cE2};
constexpr int JB[8]  = {391, 98, 25, 98, 25, 391, 98, 25};
constexpr int JBBASE[9] = {0, 391, 489, 514, 612, 637, 1028, 1126, 1151};
constexpr int TB = 1151;          // total buckets
constexpr int JCB[8] = {293, 74, 19, 49, 13, 293, 74, 19};
constexpr int JCBASE[9] = {0, 293, 367, 386, 435, 448, 741, 815, 834};
constexpr int TCB = 834;          // total chunk blocks
constexpr int CHUNK = 2048;
constexpr int BSTRIDE = 400;      // cntCB row stride (>= max JB)

// dst-side edge bases (also CSR pair bases) + node-offset bases (off array)
constexpr int EBASE[5]   = {0, 600000, 750000, 787500, 887500};
constexpr int E_TOTAL    = 912500;
constexpr int SBASE[3]   = {0, 600000, 750000};
constexpr int S_TOTAL    = 787500;
constexpr int NBASE[5]   = {0, 100096, 125184, 131584, 156672};
constexpr int NPAD_TOTAL = 163072;
constexpr int DEGBASE[3] = {0, 100000, 125000};
constexpr int DEG_TOTAL  = 131250;
}

typedef __attribute__((ext_vector_type(8))) short short8;
typedef __attribute__((ext_vector_type(4))) float floatx4;

__device__ inline ushort f2bf(float f) {
  union { float f; unsigned u; } v; v.f = f;
  unsigned u = v.u;
  return (ushort)((u + 0x7FFFu + ((u >> 16) & 1u)) >> 16);
}

__device__ inline int job_of_cb(int cb) {
  int j = 0;
  while (cb >= JCBASE[j + 1]) ++j;
  return j;
}
__device__ inline int job_of_bucket(int g) {
  int j = 0;
  while (g >= JBBASE[j + 1]) ++j;
  return j;
}

// ---------------- phase C1: per-chunk coarse bucket counts ----------------
__global__ __launch_bounds__(256) void c1_count_kernel(
    const int* __restrict__ k0, const int* __restrict__ k1, const int* __restrict__ k2,
    const int* __restrict__ k3, const int* __restrict__ k4, const int* __restrict__ k5,
    const int* __restrict__ k6, const int* __restrict__ k7,
    int* __restrict__ cntCB) {
  __shared__ int cnt[BSTRIDE];
  int cb = blockIdx.x;
  int j = job_of_cb(cb);
  int lb = cb - JCBASE[j];
  const int* keys;
  switch (j) {
    case 0: keys = k0; break; case 1: keys = k1; break; case 2: keys = k2; break;
    case 3: keys = k3; break; case 4: keys = k4; break; case 5: keys = k5; break;
    case 6: keys = k6; break; default: keys = k7; break;
  }
  int nB = JB[j];
  for (int b = threadIdx.x; b < nB; b += 256) cnt[b] = 0;
  __syncthreads();
  int e0 = lb * CHUNK;
  int e1 = min(e0 + CHUNK, JE[j]);
  for (int e = e0 + threadIdx.x; e < e1; e += 256)
    atomicAdd(&cnt[keys[e] >> 8], 1);
  __syncthreads();
  for (int b = threadIdx.x; b < nB; b += 256)
    cntCB[cb * BSTRIDE + b] = cnt[b];
}

// ---------------- phase C2a: scan each bucket across its chunks ----------------
__global__ __launch_bounds__(256) void c2a_scan_kernel(int* __restrict__ cntCB,
                                                       int* __restrict__ bucketTot) {
  __shared__ int s[256];
  int g = blockIdx.x;
  int j = job_of_bucket(g);
  int b = g - JBBASE[j];
  int cb0 = JCBASE[j], nCB = JCB[j];
  int carry = 0;
  for (int c0 = 0; c0 < nCB; c0 += 256) {
    int i = c0 + threadIdx.x;
    int v = (i < nCB) ? cntCB[(cb0 + i) * BSTRIDE + b] : 0;
    s[threadIdx.x] = v;
    __syncthreads();
    for (int d = 1; d < 256; d <<= 1) {
      int t = (threadIdx.x >= d) ? s[threadIdx.x - d] : 0;
      __syncthreads();
      s[threadIdx.x] += t;
      __syncthreads();
    }
    if (i < nCB) cntCB[(cb0 + i) * BSTRIDE + b] = carry + s[threadIdx.x] - v;
    carry += s[255];
    __syncthreads();
  }
  if (threadIdx.x == 0) bucketTot[g] = carry;
}

// ---------------- phase C2b: per-job exclusive scan over buckets ----------------
__global__ __launch_bounds__(256) void c2b_scan_kernel(const int* __restrict__ bucketTot,
                                                       int* __restrict__ bucketBase) {
  __shared__ int s[256];
  int j = blockIdx.x;
  int g0 = JBBASE[j], nB = JB[j];
  int carry = 0;
  for (int c0 = 0; c0 < nB; c0 += 256) {
    int i = c0 + threadIdx.x;
    int v = (i < nB) ? bucketTot[g0 + i] : 0;
    s[threadIdx.x] = v;
    __syncthreads();
    for (int d = 1; d < 256; d <<= 1) {
      int t = (threadIdx.x >= d) ? s[threadIdx.x - d] : 0;
      __syncthreads();
      s[threadIdx.x] += t;
      __syncthreads();
    }
    if (i < nB) bucketBase[g0 + i] = carry + s[threadIdx.x] - v;
    carry += s[255];
    __syncthreads();
  }
}

// ---------------- phase C3 (src side): scatter s_local into bucket order ----------------
__global__ __launch_bounds__(256) void c3_src_kernel(
    const int* __restrict__ s0, const int* __restrict__ s1, const int* __restrict__ s2,
    const int* __restrict__ cntCB, const int* __restrict__ bucketBase,
    int* __restrict__ scatSrc) {
  __shared__ int base[BSTRIDE];
  int cb = blockIdx.x + JCBASE[5];
  int j = job_of_cb(cb);           // 5..7
  int lb = cb - JCBASE[j];
  const int* keys = (j == 5) ? s0 : (j == 6) ? s1 : s2;
  int nB = JB[j];
  for (int b = threadIdx.x; b < nB; b += 256)
    base[b] = SBASE[j - 5] + bucketBase[JBBASE[j] + b] + cntCB[cb * BSTRIDE + b];
  __syncthreads();
  int e0 = lb * CHUNK;
  int e1 = min(e0 + CHUNK, JE[j]);
  for (int e = e0 + threadIdx.x; e < e1; e += 256) {
    int s = keys[e];
    int pos = atomicAdd(&base[s >> 8], 1);
    scatSrc[pos] = s & 255;
  }
}

// ---------------- phase Ddeg: exact per-node degree -> dinv ----------------
__global__ __launch_bounds__(256) void ddeg_kernel(const int* __restrict__ scatSrc,
                                                   const int* __restrict__ bucketTot,
                                                   const int* __restrict__ bucketBase,
                                                   float* __restrict__ dinv) {
  __shared__ int cnt[256];
  int g = blockIdx.x + JBBASE[5];
  int j = job_of_bucket(g);        // 5..7
  int b = g - JBBASE[j];
  int st = SBASE[j - 5] + bucketBase[g];
  int en = st + bucketTot[g];
  cnt[threadIdx.x] = 0;
  __syncthreads();
  for (int idx = st + threadIdx.x; idx < en; idx += 256)
    atomicAdd(&cnt[scatSrc[idx]], 1);
  __syncthreads();
  int node = b * 256 + threadIdx.x;
  if (node < JN[j]) {
    int c = cnt[threadIdx.x];
    dinv[DEGBASE[j - 5] + node] = (c > 0) ? rsqrtf((float)c) : 0.f;
  }
}

// ---------------- phase C3 (dst side): scatter (packed, w) ----------------
__global__ __launch_bounds__(256) void c3_dst_kernel(
    const int* __restrict__ d0, const int* __restrict__ s0,
    const int* __restrict__ d1, const int* __restrict__ s1,
    const int* __restrict__ d2, const int* __restrict__ s2,
    const int* __restrict__ p0r, const int* __restrict__ p0c, const float* __restrict__ p0v,
    const int* __restrict__ p1r, const int* __restrict__ p1c, const float* __restrict__ p1v,
    const float* __restrict__ dinv,
    const int* __restrict__ cntCB, const int* __restrict__ bucketBase,
    int2* __restrict__ scatPairs) {
  __shared__ int base[BSTRIDE];
  int cb = blockIdx.x;
  int j = job_of_cb(cb);           // 0..4
  int lb = cb - JCBASE[j];
  const int* dk; const int* sk; const float* vv = nullptr;
  switch (j) {
    case 0: dk = d0; sk = s0; break;
    case 1: dk = d1; sk = s1; break;
    case 2: dk = d2; sk = s2; break;
    case 3: dk = p0r; sk = p0c; vv = p0v; break;
    default: dk = p1r; sk = p1c; vv = p1v; break;
  }
  int nB = JB[j];
  for (int b = threadIdx.x; b < nB; b += 256)
    base[b] = EBASE[j] + bucketBase[JBBASE[j] + b] + cntCB[cb * BSTRIDE + b];
  __syncthreads();
  int e0 = lb * CHUNK;
  int e1 = min(e0 + CHUNK, JE[j]);
  for (int e = e0 + threadIdx.x; e < e1; e += 256) {
    int d = dk[e];
    int s = sk[e];
    float w;
    if (j < 3) w = -(dinv[DEGBASE[j] + s] * dinv[DEGBASE[j] + d]);
    else w = vv[e];
    int pos = atomicAdd(&base[d >> 8], 1);
    scatPairs[pos] = make_int2(((d & 255) << 17) | s, __float_as_int(w));
  }
}

// ---------------- phase Dcsr: per-bucket exact CSR ----------------
__global__ __launch_bounds__(256) void dcsr_kernel(const int2* __restrict__ scatPairs,
                                                   const int* __restrict__ bucketTot,
                                                   const int* __restrict__ bucketBase,
                                                   int* __restrict__ off,
                                                   int2* __restrict__ csrPairs) {
  __shared__ int cnt[256];
  __shared__ int sArr[256];
  __shared__ int cur[256];
  int g = blockIdx.x;
  int j = job_of_bucket(g);        // 0..4
  int b = g - JBBASE[j];
  int relBase = bucketBase[g];     // job-relative edge offset of this bucket
  int st = EBASE[j] + relBase;
  int en = st + bucketTot[g];
  cnt[threadIdx.x] = 0;
  __syncthreads();
  for (int idx = st + threadIdx.x; idx < en; idx += 256)
    atomicAdd(&cnt[scatPairs[idx].x >> 17], 1);
  __syncthreads();
  int v = cnt[threadIdx.x];
  sArr[threadIdx.x] = v;
  __syncthreads();
  for (int d = 1; d < 256; d <<= 1) {
    int t = (threadIdx.x >= d) ? sArr[threadIdx.x - d] : 0;
    __syncthreads();
    sArr[threadIdx.x] += t;
    __syncthreads();
  }
  int excl = sArr[threadIdx.x] - v;
  int node = b * 256 + threadIdx.x;
  if (node < JN[j]) off[NBASE[j] + node] = relBase + excl;
  if (threadIdx.x == 0 && b == JB[j] - 1) off[NBASE[j] + JN[j]] = JE[j];
  cur[threadIdx.x] = st + excl;    // absolute final position cursor
  __syncthreads();
  for (int idx = st + threadIdx.x; idx < en; idx += 256) {
    int2 p = scatPairs[idx];
    int dl = p.x >> 17;
    int s = p.x & 0x1FFFF;
    int pos = atomicAdd(&cur[dl], 1);
    csrPairs[pos] = make_int2(s, p.y);
  }
}

// ---------------- props (unchanged) ----------------
__global__ __launch_bounds__(256) void csr_prop128_kernel(
    const int* __restrict__ off, const int2* __restrict__ pairs,
    const float* __restrict__ h, float* __restrict__ y,
    const float* __restrict__ prev, float scale, int N) {
  int r = blockIdx.x * 2 + (threadIdx.x >> 7);
  int f = threadIdx.x & 127;
  if (r >= N) return;
  int s = off[r], e = off[r + 1];
  float acc = 0.f;
  for (int j = s; j < e; ++j) {
    int2 p = pairs[j];
    acc += __int_as_float(p.y) * h[(size_t)p.x * 128 + f];
  }
  float v = scale * acc;
  if (prev) v -= prev[(size_t)r * 128 + f];
  y[(size_t)r * 128 + f] = v;
}

__global__ void csr_prop3_kernel(const int* __restrict__ off, const int2* __restrict__ pairs,
                                 const float* __restrict__ h, int hs, int ho,
                                 float* __restrict__ y, int yo,
                                 const float* __restrict__ prev, int po,
                                 float scale, int N) {
  int r = blockIdx.x * blockDim.x + threadIdx.x;
  if (r >= N) return;
  int s = off[r], e = off[r + 1];
  float a0 = 0.f, a1 = 0.f, a2 = 0.f;
  for (int j = s; j < e; ++j) {
    int2 p = pairs[j];
    float w = __int_as_float(p.y);
    const float* hp = h + (size_t)p.x * hs + ho;
    a0 += w * hp[0]; a1 += w * hp[1]; a2 += w * hp[2];
  }
  a0 *= scale; a1 *= scale; a2 *= scale;
  if (prev) {
    const float* pp = prev + (size_t)r * 18 + po;
    a0 -= pp[0]; a1 -= pp[1]; a2 -= pp[2];
  }
  float* yp = y + (size_t)r * 18 + yo;
  yp[0] = a0; yp[1] = a1; yp[2] = a2;
}

__global__ void copyx_kernel(const float* __restrict__ x, float* __restrict__ Tb, int n3) {
  int i = blockIdx.x * blockDim.x + threadIdx.x;
  if (i < n3) {
    int r = i / 3, c = i - r * 3;
    Tb[(size_t)r * 18 + c] = x[i];
  }
}

// ---------------- GEMMs (unchanged) ----------------
__global__ __launch_bounds__(256) void gemm18_kernel(
    const float* __restrict__ Tb, const float* __restrict__ W,
    const float* __restrict__ bias, float* __restrict__ C, int M) {
  __shared__ float Wl[18 * 128];
  for (int i = threadIdx.x; i < 18 * 128; i += 256) Wl[i] = W[i];
  __syncthreads();
  int idx = blockIdx.x * 256 + threadIdx.x;
  int r = idx >> 5;
  int c4 = (idx & 31) << 2;
  if (r >= M) return;
  const float* a = Tb + (size_t)r * 18;
  float4 acc = *(const float4*)(bias + c4);
#pragma unroll
  for (int t = 0; t < 18; ++t) {
    float av = a[t];
    float4 wv = *(const float4*)&Wl[t * 128 + c4];
    acc.x += av * wv.x; acc.y += av * wv.y;
    acc.z += av * wv.z; acc.w += av * wv.w;
  }
  acc.x = fmaxf(acc.x, 0.f); acc.y = fmaxf(acc.y, 0.f);
  acc.z = fmaxf(acc.z, 0.f); acc.w = fmaxf(acc.w, 0.f);
  *(float4*)(C + (size_t)r * 128 + c4) = acc;
}

__global__ void prep_w_kernel(const float* __restrict__ W, ushort* __restrict__ Wt, int N) {
  int i = blockIdx.x * 256 + threadIdx.x;
  if (i >= 768 * N) return;
  int k = i / N, n = i - k * N;
  Wt[(size_t)n * 768 + k] = f2bf(W[i]);
}

template <int RELU>
__global__ __launch_bounds__(256, 2) void gemm_mfma_kernel(
    const float* __restrict__ T, const ushort* __restrict__ Wt,
    const float* __restrict__ bias, float* __restrict__ C, int M, int N) {
  __shared__ ushort Al[64][40];
  __shared__ ushort Bl[128][40];
  const int tid = threadIdx.x;
  const int rowBase = blockIdx.x * 64;
  const int colBase = blockIdx.y * 128;
  const int wave = tid >> 6;
  const int lane = tid & 63;
  const int m16 = lane & 15;
  const int quad = lane >> 4;
  const size_t Mstride = (size_t)M * 128;

  floatx4 acc[8];
#pragma unroll
  for (int c = 0; c < 8; ++c)
#pragma unroll
    for (int r = 0; r < 4; ++r) acc[c][r] = 0.f;

  const int sRow = tid >> 2;
  const int sK8 = (tid & 3) * 8;
  const int growA = rowBase + sRow;
  const bool aValid = growA < M;

  for (int kc = 0; kc < 24; ++kc) {
    unsigned p0 = 0, p1 = 0, p2 = 0, p3 = 0;
    if (aValid) {
      const float* ap = T + (size_t)(kc >> 2) * Mstride + (size_t)growA * 128
                        + ((kc & 3) << 5) + sK8;
      float4 v0 = *(const float4*)ap;
      float4 v1 = *(const float4*)(ap + 4);
      p0 = f2bf(v0.x) | ((unsigned)f2bf(v0.y) << 16);
      p1 = f2bf(v0.z) | ((unsigned)f2bf(v0.w) << 16);
      p2 = f2bf(v1.x) | ((unsigned)f2bf(v1.y) << 16);
      p3 = f2bf(v1.z) | ((unsigned)f2bf(v1.w) << 16);
    }
    *(uint4*)&Al[sRow][sK8] = make_uint4(p0, p1, p2, p3);
#pragma unroll
    for (int l = 0; l < 2; ++l) {
      int lin = tid + l * 256;
      int bRow = lin >> 2;
      int bK8 = (lin & 3) * 8;
      *(uint4*)&Bl[bRow][bK8] =
          *(const uint4*)(Wt + (size_t)(colBase + bRow) * 768 + kc * 32 + bK8);
    }
    __syncthreads();

    short8 a = *(const short8*)&Al[wave * 16 + m16][quad * 8];
#pragma unroll
    for (int c = 0; c < 8; ++c) {
      short8 b = *(const short8*)&Bl[c * 16 + m16][quad * 8];
      acc[c] = __builtin_amdgcn_mfma_f32_16x16x32_bf16(a, b, acc[c], 0, 0, 0);
    }
    __syncthreads();
  }

#pragma unroll
  for (int c = 0; c < 8; ++c) {
    int col = colBase + c * 16 + m16;
    float bv = bias[col];
#pragma unroll
    for (int r = 0; r < 4; ++r) {
      int row = rowBase + wave * 16 + quad * 4 + r;
      if (row < M) {
        float v = acc[c][r] + bv;
        if (RELU) v = fmaxf(v, 0.f);
        C[(size_t)row * N + col] = v;
      }
    }
  }
}

// ---------------- linear head (unchanged) ----------------
__global__ void initout_kernel(float* __restrict__ out, const float* __restrict__ linb) {
  int i = threadIdx.x;
  if (i < 10) out[i] = linb[i];
}

__global__ __launch_bounds__(256) void linear_kernel(const float* __restrict__ Wl,
                                                     const float* __restrict__ h,
                                                     float* __restrict__ out, int D) {
  float p[10];
#pragma unroll
  for (int j = 0; j < 10; ++j) p[j] = 0.f;
  int stride = gridDim.x * blockDim.x;
  for (int i = blockIdx.x * blockDim.x + threadIdx.x; i < D; i += stride) {
    float hv = h[i];
#pragma unroll
    for (int j = 0; j < 10; ++j) p[j] += Wl[(size_t)j * D + i] * hv;
  }
#pragma unroll
  for (int j = 0; j < 10; ++j) {
#pragma unroll
    for (int off = 32; off > 0; off >>= 1) p[j] += __shfl_down(p[j], off, 64);
  }
  __shared__ float s[4][10];
  int wave = threadIdx.x >> 6, lane = threadIdx.x & 63;
  if (lane == 0) {
#pragma unroll
    for (int j = 0; j < 10; ++j) s[wave][j] = p[j];
  }
  __syncthreads();
  if (threadIdx.x < 10) {
    float t = s[0][threadIdx.x] + s[1][threadIdx.x] + s[2][threadIdx.x] + s[3][threadIdx.x];
    atomicAdd(&out[threadIdx.x], t);
  }
}

// ---------------- host orchestration ----------------
extern "C" void kernel_launch(void* const* d_in, const int* in_sizes, int n_in,
                              void* d_out, int out_size, void* d_ws, size_t ws_size,
                              hipStream_t stream) {
  const float* x    = (const float*)d_in[0];
  const int*   ei0  = (const int*)d_in[1];
  const int*   ei1  = (const int*)d_in[2];
  const int*   ei2  = (const int*)d_in[3];
  const float* W0   = (const float*)d_in[4];
  const float* b0   = (const float*)d_in[5];
  const float* W1   = (const float*)d_in[6];
  const float* b1   = (const float*)d_in[7];
  const float* W2   = (const float*)d_in[8];
  const float* b2   = (const float*)d_in[9];
  const int*   D0r  = (const int*)d_in[10];
  const int*   D0c  = (const int*)d_in[11];
  const float* D0v  = (const float*)d_in[12];
  const int*   D1r  = (const int*)d_in[13];
  const int*   D1c  = (const int*)d_in[14];
  const float* D1v  = (const float*)d_in[15];
  const float* linW = (const float*)d_in[16];
  const float* linb = (const float*)d_in[17];
  float* out = (float*)d_out;
  (void)in_sizes; (void)n_in; (void)out_size; (void)ws_size;

  const int* src0 = ei0;            const int* dst0 = ei0 + cE0;
  const int* src1 = ei1;            const int* dst1 = ei1 + cE1;
  const int* src2 = ei2;            const int* dst2 = ei2 + cE2;

  float* ws = (float*)d_ws;
  size_t off = 0;
  auto alloc = [&](size_t n) {
    float* p = ws + off;
    off += (n + 63) & ~size_t(63);
    return p;
  };
  float* dinv       = alloc(DEG_TOTAL);
  int*   cntCB      = (int*)alloc((size_t)TCB * BSTRIDE);
  int*   bucketTot  = (int*)alloc(TB);
  int*   bucketBase = (int*)alloc(TB);
  int*   scatSrc    = (int*)alloc(S_TOTAL);
  int2*  scatPairs  = (int2*)alloc((size_t)2 * E_TOTAL);
  int2*  csrPairs   = (int2*)alloc((size_t)2 * E_TOTAL);
  int*   offArr     = (int*)alloc(NPAD_TOTAL);
  ushort* Wt1       = (ushort*)alloc(768 * 128 / 2);
  ushort* Wt2       = (ushort*)alloc(768 * 256 / 2);
  float* Tbuf0      = alloc((size_t)cN0 * 18);
  float* out0       = alloc((size_t)cN0 * 128);
  float* Tlvl1      = alloc((size_t)6 * cN1 * 128);
  float* out1       = alloc((size_t)cN1 * 128);
  float* Tlvl2      = alloc((size_t)6 * cN2 * 128);
  float* out2       = alloc((size_t)cN2 * 256);

  auto nb = [](long long n) { return (unsigned)((n + 255) / 256); };

  // ---- atomic-free CSR build ----
  c1_count_kernel<<<TCB, 256, 0, stream>>>(dst0, dst1, dst2, D0r, D1r,
                                           src0, src1, src2, cntCB);
  c2a_scan_kernel<<<TB, 256, 0, stream>>>(cntCB, bucketTot);
  c2b_scan_kernel<<<8, 256, 0, stream>>>(bucketTot, bucketBase);
  c3_src_kernel<<<TCB - JCBASE[5], 256, 0, stream>>>(src0, src1, src2,
                                                     cntCB, bucketBase, scatSrc);
  ddeg_kernel<<<TB - JBBASE[5], 256, 0, stream>>>(scatSrc, bucketTot, bucketBase, dinv);
  c3_dst_kernel<<<JCBASE[5], 256, 0, stream>>>(dst0, src0, dst1, src1, dst2, src2,
                                               D0r, D0c, D0v, D1r, D1c, D1v,
                                               dinv, cntCB, bucketBase, scatPairs);
  dcsr_kernel<<<JBBASE[5], 256, 0, stream>>>(scatPairs, bucketTot, bucketBase,
                                             offArr, csrPairs);
  prep_w_kernel<<<nb(768 * 128), 256, 0, stream>>>(W1, Wt1, 128);
  prep_w_kernel<<<nb(768 * 256), 256, 0, stream>>>(W2, Wt2, 256);

  auto seg_off   = [&](int s) { return offArr + NBASE[s]; };
  auto seg_pairs = [&](int s) { return csrPairs + EBASE[s]; };

  // ================= Level 0 (F=3 -> 128) =================
  copyx_kernel<<<nb((long long)cN0 * 3), 256, 0, stream>>>(x, Tbuf0, cN0 * 3);
  csr_prop3_kernel<<<nb(cN0), 256, 0, stream>>>(seg_off(0), seg_pairs(0),
      x, 3, 0, Tbuf0, 3, nullptr, 0, 1.f, cN0);
  csr_prop3_kernel<<<nb(cN0), 256, 0, stream>>>(seg_off(0), seg_pairs(0),
      Tbuf0, 18, 3, Tbuf0, 6, Tbuf0, 0, 2.f, cN0);
  csr_prop3_kernel<<<nb(cN0), 256, 0, stream>>>(seg_off(0), seg_pairs(0),
      Tbuf0, 18, 6, Tbuf0, 9, Tbuf0, 3, 2.f, cN0);
  csr_prop3_kernel<<<nb(cN0), 256, 0, stream>>>(seg_off(0), seg_pairs(0),
      Tbuf0, 18, 9, Tbuf0, 12, Tbuf0, 6, 2.f, cN0);
  csr_prop3_kernel<<<nb(cN0), 256, 0, stream>>>(seg_off(0), seg_pairs(0),
      Tbuf0, 18, 12, Tbuf0, 15, Tbuf0, 9, 2.f, cN0);
  gemm18_kernel<<<nb((long long)cN0 * 32), 256, 0, stream>>>(Tbuf0, W0, b0, out0, cN0);

  // pool0 -> Tlvl1 block 0
  csr_prop128_kernel<<<nb((long long)cN1 * 128), 256, 0, stream>>>(
      seg_off(3), seg_pairs(3), out0, Tlvl1, nullptr, 1.f, cN1);

  // ================= Level 1 =================
  {
    auto Tk = [&](int k) { return Tlvl1 + (size_t)k * cN1 * 128; };
    auto prop = [&](const float* hin, float* yout, const float* prev, float scale) {
      csr_prop128_kernel<<<nb((long long)cN1 * 128), 256, 0, stream>>>(
          seg_off(1), seg_pairs(1), hin, yout, prev, scale, cN1);
    };
    prop(Tk(0), Tk(1), nullptr, 1.f);
    prop(Tk(1), Tk(2), Tk(0), 2.f);
    prop(Tk(2), Tk(3), Tk(1), 2.f);
    prop(Tk(3), Tk(4), Tk(2), 2.f);
    prop(Tk(4), Tk(5), Tk(3), 2.f);
    dim3 g((cN1 + 63) / 64, 1);
    gemm_mfma_kernel<1><<<g, 256, 0, stream>>>(Tlvl1, Wt1, b1, out1, cN1, 128);
  }

  // pool1 -> Tlvl2 block 0
  csr_prop128_kernel<<<nb((long long)cN2 * 128), 256, 0, stream>>>(
      seg_off(4), seg_pairs(4), out1, Tlvl2, nullptr, 1.f, cN2);

  // ================= Level 2 (no relu, N=256) =================
  {
    auto Tk = [&](int k) { return Tlvl2 + (size_t)k * cN2 * 128; };
    auto prop = [&](const float* hin, float* yout, const float* prev, float scale) {
      csr_prop128_kernel<<<nb((long long)cN2 * 128), 256, 0, stream>>>(
          seg_off(2), seg_pairs(2), hin, yout, prev, scale, cN2);
    };
    prop(Tk(0), Tk(1), nullptr, 1.f);
    prop(Tk(1), Tk(2), Tk(0), 2.f);
    prop(Tk(2), Tk(3), Tk(1), 2.f);
    prop(Tk(3), Tk(4), Tk(2), 2.f);
    prop(Tk(4), Tk(5), Tk(3), 2.f);
    dim3 g((cN2 + 63) / 64, 2);
    gemm_mfma_kernel<0><<<g, 256, 0, stream>>>(Tlvl2, Wt2, b2, out2, cN2, 256);
  }

  // ---- linear head ----
  initout_kernel<<<1, 64, 0, stream>>>(out, linb);
  linear_kernel<<<512, 256, 0, stream>>>(linW, out2, out, cD);
}

// Round 7
// 465.725 us; speedup vs baseline: 2.7892x; 1.3896x over previous
//
#include <hip/hip_runtime.h>

// ChebClassifier R7: float4 props (32 lanes/row, edge-unrolled), padded
// [6][N][4] level-0 T layout, fused gemm18+pool0 (register-held W0 column),
// bf16 T shadows written by props so the MFMA GEMM stages without convert.

namespace {
constexpr int cN0 = 100000, cN1 = 25000, cN2 = 6250;
constexpr int cE0 = 600000, cE1 = 150000, cE2 = 37500;
constexpr int cD  = cN2 * 256;

constexpr int JN[8]  = {cN0, cN1, cN2, cN1, cN2, cN0, cN1, cN2};
constexpr int JE[8]  = {cE0, cE1, cE2, 100000, 25000, cE0, cE1, cE2};
constexpr int JB[8]  = {391, 98, 25, 98, 25, 391, 98, 25};
constexpr int JBBASE[9] = {0, 391, 489, 514, 612, 637, 1028, 1126, 1151};
constexpr int TB = 1151;
constexpr int JCB[8] = {293, 74, 19, 49, 13, 293, 74, 19};
constexpr int JCBASE[9] = {0, 293, 367, 386, 435, 448, 741, 815, 834};
constexpr int TCB = 834;
constexpr int CHUNK = 2048;
constexpr int BSTRIDE = 400;

constexpr int EBASE[5]   = {0, 600000, 750000, 787500, 887500};
constexpr int E_TOTAL    = 912500;
constexpr int SBASE[3]   = {0, 600000, 750000};
constexpr int S_TOTAL    = 787500;
constexpr int NBASE[5]   = {0, 100096, 125184, 131584, 156672};
constexpr int NPAD_TOTAL = 163072;
constexpr int DEGBASE[3] = {0, 100000, 125000};
constexpr int DEG_TOTAL  = 131250;
}

typedef __attribute__((ext_vector_type(8))) short short8;
typedef __attribute__((ext_vector_type(4))) float floatx4;

__device__ inline ushort f2bf(float f) {
  union { float f; unsigned u; } v; v.f = f;
  unsigned u = v.u;
  return (ushort)((u + 0x7FFFu + ((u >> 16) & 1u)) >> 16);
}

__device__ inline int job_of_cb(int cb) {
  int j = 0;
  while (cb >= JCBASE[j + 1]) ++j;
  return j;
}
__device__ inline int job_of_bucket(int g) {
  int j = 0;
  while (g >= JBBASE[j + 1]) ++j;
  return j;
}

// ---------------- atomic-free CSR build (unchanged from R6) ----------------
__global__ __launch_bounds__(256) void c1_count_kernel(
    const int* __restrict__ k0, const int* __restrict__ k1, const int* __restrict__ k2,
    const int* __restrict__ k3, const int* __restrict__ k4, const int* __restrict__ k5,
    const int* __restrict__ k6, const int* __restrict__ k7,
    int* __restrict__ cntCB) {
  __shared__ int cnt[BSTRIDE];
  int cb = blockIdx.x;
  int j = job_of_cb(cb);
  int lb = cb - JCBASE[j];
  const int* keys;
  switch (j) {
    case 0: keys = k0; break; case 1: keys = k1; break; case 2: keys = k2; break;
    case 3: keys = k3; break; case 4: keys = k4; break; case 5: keys = k5; break;
    case 6: keys = k6; break; default: keys = k7; break;
  }
  int nB = JB[j];
  for (int b = threadIdx.x; b < nB; b += 256) cnt[b] = 0;
  __syncthreads();
  int e0 = lb * CHUNK;
  int e1 = min(e0 + CHUNK, JE[j]);
  for (int e = e0 + threadIdx.x; e < e1; e += 256)
    atomicAdd(&cnt[keys[e] >> 8], 1);
  __syncthreads();
  for (int b = threadIdx.x; b < nB; b += 256)
    cntCB[cb * BSTRIDE + b] = cnt[b];
}

__global__ __launch_bounds__(256) void c2a_scan_kernel(int* __restrict__ cntCB,
                                                       int* __restrict__ bucketTot) {
  __shared__ int s[256];
  int g = blockIdx.x;
  int j = job_of_bucket(g);
  int b = g - JBBASE[j];
  int cb0 = JCBASE[j], nCB = JCB[j];
  int carry = 0;
  for (int c0 = 0; c0 < nCB; c0 += 256) {
    int i = c0 + threadIdx.x;
    int v = (i < nCB) ? cntCB[(cb0 + i) * BSTRIDE + b] : 0;
    s[threadIdx.x] = v;
    __syncthreads();
    for (int d = 1; d < 256; d <<= 1) {
      int t = (threadIdx.x >= d) ? s[threadIdx.x - d] : 0;
      __syncthreads();
      s[threadIdx.x] += t;
      __syncthreads();
    }
    if (i < nCB) cntCB[(cb0 + i) * BSTRIDE + b] = carry + s[threadIdx.x] - v;
    carry += s[255];
    __syncthreads();
  }
  if (threadIdx.x == 0) bucketTot[g] = carry;
}

__global__ __launch_bounds__(256) void c2b_scan_kernel(const int* __restrict__ bucketTot,
                                                       int* __restrict__ bucketBase) {
  __shared__ int s[256];
  int j = blockIdx.x;
  int g0 = JBBASE[j], nB = JB[j];
  int carry = 0;
  for (int c0 = 0; c0 < nB; c0 += 256) {
    int i = c0 + threadIdx.x;
    int v = (i < nB) ? bucketTot[g0 + i] : 0;
    s[threadIdx.x] = v;
    __syncthreads();
    for (int d = 1; d < 256; d <<= 1) {
      int t = (threadIdx.x >= d) ? s[threadIdx.x - d] : 0;
      __syncthreads();
      s[threadIdx.x] += t;
      __syncthreads();
    }
    if (i < nB) bucketBase[g0 + i] = carry + s[threadIdx.x] - v;
    carry += s[255];
    __syncthreads();
  }
}

__global__ __launch_bounds__(256) void c3_src_kernel(
    const int* __restrict__ s0, const int* __restrict__ s1, const int* __restrict__ s2,
    const int* __restrict__ cntCB, const int* __restrict__ bucketBase,
    int* __restrict__ scatSrc) {
  __shared__ int base[BSTRIDE];
  int cb = blockIdx.x + JCBASE[5];
  int j = job_of_cb(cb);
  int lb = cb - JCBASE[j];
  const int* keys = (j == 5) ? s0 : (j == 6) ? s1 : s2;
  int nB = JB[j];
  for (int b = threadIdx.x; b < nB; b += 256)
    base[b] = SBASE[j - 5] + bucketBase[JBBASE[j] + b] + cntCB[cb * BSTRIDE + b];
  __syncthreads();
  int e0 = lb * CHUNK;
  int e1 = min(e0 + CHUNK, JE[j]);
  for (int e = e0 + threadIdx.x; e < e1; e += 256) {
    int s = keys[e];
    int pos = atomicAdd(&base[s >> 8], 1);
    scatSrc[pos] = s & 255;
  }
}

__global__ __launch_bounds__(256) void ddeg_kernel(const int* __restrict__ scatSrc,
                                                   const int* __restrict__ bucketTot,
                                                   const int* __restrict__ bucketBase,
                                                   float* __restrict__ dinv) {
  __shared__ int cnt[256];
  int g = blockIdx.x + JBBASE[5];
  int j = job_of_bucket(g);
  int b = g - JBBASE[j];
  int st = SBASE[j - 5] + bucketBase[g];
  int en = st + bucketTot[g];
  cnt[threadIdx.x] = 0;
  __syncthreads();
  for (int idx = st + threadIdx.x; idx < en; idx += 256)
    atomicAdd(&cnt[scatSrc[idx]], 1);
  __syncthreads();
  int node = b * 256 + threadIdx.x;
  if (node < JN[j]) {
    int c = cnt[threadIdx.x];
    dinv[DEGBASE[j - 5] + node] = (c > 0) ? rsqrtf((float)c) : 0.f;
  }
}

__global__ __launch_bounds__(256) void c3_dst_kernel(
    const int* __restrict__ d0, const int* __restrict__ s0,
    const int* __restrict__ d1, const int* __restrict__ s1,
    const int* __restrict__ d2, const int* __restrict__ s2,
    const int* __restrict__ p0r, const int* __restrict__ p0c, const float* __restrict__ p0v,
    const int* __restrict__ p1r, const int* __restrict__ p1c, const float* __restrict__ p1v,
    const float* __restrict__ dinv,
    const int* __restrict__ cntCB, const int* __restrict__ bucketBase,
    int2* __restrict__ scatPairs) {
  __shared__ int base[BSTRIDE];
  int cb = blockIdx.x;
  int j = job_of_cb(cb);
  int lb = cb - JCBASE[j];
  const int* dk; const int* sk; const float* vv = nullptr;
  switch (j) {
    case 0: dk = d0; sk = s0; break;
    case 1: dk = d1; sk = s1; break;
    case 2: dk = d2; sk = s2; break;
    case 3: dk = p0r; sk = p0c; vv = p0v; break;
    default: dk = p1r; sk = p1c; vv = p1v; break;
  }
  int nB = JB[j];
  for (int b = threadIdx.x; b < nB; b += 256)
    base[b] = EBASE[j] + bucketBase[JBBASE[j] + b] + cntCB[cb * BSTRIDE + b];
  __syncthreads();
  int e0 = lb * CHUNK;
  int e1 = min(e0 + CHUNK, JE[j]);
  for (int e = e0 + threadIdx.x; e < e1; e += 256) {
    int d = dk[e];
    int s = sk[e];
    float w;
    if (j < 3) w = -(dinv[DEGBASE[j] + s] * dinv[DEGBASE[j] + d]);
    else w = vv[e];
    int pos = atomicAdd(&base[d >> 8], 1);
    scatPairs[pos] = make_int2(((d & 255) << 17) | s, __float_as_int(w));
  }
}

__global__ __launch_bounds__(256) void dcsr_kernel(const int2* __restrict__ scatPairs,
                                                   const int* __restrict__ bucketTot,
                                                   const int* __restrict__ bucketBase,
                                                   int* __restrict__ off,
                                                   int2* __restrict__ csrPairs) {
  __shared__ int cnt[256];
  __shared__ int sArr[256];
  __shared__ int cur[256];
  int g = blockIdx.x;
  int j = job_of_bucket(g);
  int b = g - JBBASE[j];
  int relBase = bucketBase[g];
  int st = EBASE[j] + relBase;
  int en = st + bucketTot[g];
  cnt[threadIdx.x] = 0;
  __syncthreads();
  for (int idx = st + threadIdx.x; idx < en; idx += 256)
    atomicAdd(&cnt[scatPairs[idx].x >> 17], 1);
  __syncthreads();
  int v = cnt[threadIdx.x];
  sArr[threadIdx.x] = v;
  __syncthreads();
  for (int d = 1; d < 256; d <<= 1) {
    int t = (threadIdx.x >= d) ? sArr[threadIdx.x - d] : 0;
    __syncthreads();
    sArr[threadIdx.x] += t;
    __syncthreads();
  }
  int excl = sArr[threadIdx.x] - v;
  int node = b * 256 + threadIdx.x;
  if (node < JN[j]) off[NBASE[j] + node] = relBase + excl;
  if (threadIdx.x == 0 && b == JB[j] - 1) off[NBASE[j] + JN[j]] = JE[j];
  cur[threadIdx.x] = st + excl;
  __syncthreads();
  for (int idx = st + threadIdx.x; idx < en; idx += 256) {
    int2 p = scatPairs[idx];
    int dl = p.x >> 17;
    int s = p.x & 0x1FFFF;
    int pos = atomicAdd(&cur[dl], 1);
    csrPairs[pos] = make_int2(s, p.y);
  }
}

// ---------------- props ----------------
// 32 lanes per row, float4; writes fp32 y + bf16 shadow ybf.
__global__ __launch_bounds__(256) void csr_prop128_kernel(
    const int* __restrict__ off, const int2* __restrict__ pairs,
    const float* __restrict__ h, float* __restrict__ y, ushort* __restrict__ ybf,
    const float* __restrict__ prev, float scale, int N) {
  int r = blockIdx.x * 8 + (threadIdx.x >> 5);
  int l = threadIdx.x & 31;
  if (r >= N) return;
  int s = off[r], e = off[r + 1];
  const float4* h4 = (const float4*)h;
  float ax = 0.f, ay = 0.f, az = 0.f, aw = 0.f;
  int j = s;
  for (; j + 2 <= e; j += 2) {
    int2 p0 = pairs[j];
    int2 p1 = pairs[j + 1];
    float4 v0 = h4[(size_t)p0.x * 32 + l];
    float4 v1 = h4[(size_t)p1.x * 32 + l];
    float w0 = __int_as_float(p0.y);
    float w1 = __int_as_float(p1.y);
    ax += w0 * v0.x + w1 * v1.x;
    ay += w0 * v0.y + w1 * v1.y;
    az += w0 * v0.z + w1 * v1.z;
    aw += w0 * v0.w + w1 * v1.w;
  }
  if (j < e) {
    int2 p = pairs[j];
    float4 v0 = h4[(size_t)p.x * 32 + l];
    float w = __int_as_float(p.y);
    ax += w * v0.x; ay += w * v0.y; az += w * v0.z; aw += w * v0.w;
  }
  float4 v = make_float4(scale * ax, scale * ay, scale * az, scale * aw);
  if (prev) {
    float4 pv = ((const float4*)prev)[(size_t)r * 32 + l];
    v.x -= pv.x; v.y -= pv.y; v.z -= pv.z; v.w -= pv.w;
  }
  ((float4*)y)[(size_t)r * 32 + l] = v;
  uint2 sp = make_uint2(f2bf(v.x) | ((unsigned)f2bf(v.y) << 16),
                        f2bf(v.z) | ((unsigned)f2bf(v.w) << 16));
  ((uint2*)ybf)[(size_t)r * 32 + l] = sp;
}

// level-0: T stored [6][N0][4] fp32 (padded float4 rows)
__global__ void csr_prop3_kernel(const int* __restrict__ off, const int2* __restrict__ pairs,
                                 const float4* __restrict__ h, float4* __restrict__ y,
                                 const float4* __restrict__ prev, float scale, int N) {
  int r = blockIdx.x * blockDim.x + threadIdx.x;
  if (r >= N) return;
  int s = off[r], e = off[r + 1];
  float ax = 0.f, ay = 0.f, az = 0.f;
  int j = s;
  for (; j + 4 <= e; j += 4) {
    int2 p0 = pairs[j], p1 = pairs[j + 1], p2 = pairs[j + 2], p3 = pairs[j + 3];
    float4 h0 = h[p0.x], h1 = h[p1.x], h2 = h[p2.x], h3 = h[p3.x];
    float w0 = __int_as_float(p0.y), w1 = __int_as_float(p1.y);
    float w2 = __int_as_float(p2.y), w3 = __int_as_float(p3.y);
    ax += w0 * h0.x + w1 * h1.x + w2 * h2.x + w3 * h3.x;
    ay += w0 * h0.y + w1 * h1.y + w2 * h2.y + w3 * h3.y;
    az += w0 * h0.z + w1 * h1.z + w2 * h2.z + w3 * h3.z;
  }
  for (; j < e; ++j) {
    int2 p = pairs[j];
    float4 hv = h[p.x];
    float w = __int_as_float(p.y);
    ax += w * hv.x; ay += w * hv.y; az += w * hv.z;
  }
  float4 v = make_float4(scale * ax, scale * ay, scale * az, 0.f);
  if (prev) {
    float4 pv = prev[r];
    v.x -= pv.x; v.y -= pv.y; v.z -= pv.z;
  }
  y[r] = v;
}

__global__ void copyx_kernel(const float* __restrict__ x, float4* __restrict__ Tb, int N) {
  int r = blockIdx.x * 256 + threadIdx.x;
  if (r < N) Tb[r] = make_float4(x[3 * r], x[3 * r + 1], x[3 * r + 2], 0.f);
}

// fused gemm18 + pool0: T0out[r,f] = sum_e v * relu(b0[f] + T18[c_e] . W0[:,f])
__global__ __launch_bounds__(256) void g18pool_kernel(
    const int* __restrict__ off, const int2* __restrict__ pairs,
    const float4* __restrict__ Tb0, const float* __restrict__ W0,
    const float* __restrict__ b0, float* __restrict__ T0out,
    ushort* __restrict__ T0bf, int N, int N0) {
  int r = blockIdx.x * 2 + (threadIdx.x >> 7);
  int f = threadIdx.x & 127;
  float wcol[18];
#pragma unroll
  for (int t = 0; t < 18; ++t) wcol[t] = W0[t * 128 + f];
  float bv = b0[f];
  if (r >= N) return;
  int s = off[r], e = off[r + 1];
  float acc = 0.f;
  for (int j = s; j < e; ++j) {
    int2 p = pairs[j];
    float v = __int_as_float(p.y);
    float d = bv;
#pragma unroll
    for (int k = 0; k < 6; ++k) {
      float4 t = Tb0[(size_t)k * N0 + p.x];
      d += t.x * wcol[k * 3 + 0] + t.y * wcol[k * 3 + 1] + t.z * wcol[k * 3 + 2];
    }
    acc += v * fmaxf(d, 0.f);
  }
  T0out[(size_t)r * 128 + f] = acc;
  T0bf[(size_t)r * 128 + f] = f2bf(acc);
}

// ---------------- GEMM (bf16 A, no conversion) ----------------
__global__ void prep_w_kernel(const float* __restrict__ W1, const float* __restrict__ W2,
                              ushort* __restrict__ Wt1, ushort* __restrict__ Wt2) {
  int i = blockIdx.x * 256 + threadIdx.x;
  if (i < 768 * 128) {
    int k = i / 128, n = i - k * 128;
    Wt1[(size_t)n * 768 + k] = f2bf(W1[i]);
  } else {
    int i2 = i - 768 * 128;
    if (i2 < 768 * 256) {
      int k = i2 / 256, n = i2 - k * 256;
      Wt2[(size_t)n * 768 + k] = f2bf(W2[i2]);
    }
  }
}

template <int RELU>
__global__ __launch_bounds__(256, 2) void gemm_mfma_kernel(
    const ushort* __restrict__ Tbf, const ushort* __restrict__ Wt,
    const float* __restrict__ bias, float* __restrict__ C, int M, int N) {
  __shared__ ushort Al[64][40];
  __shared__ ushort Bl[128][40];
  const int tid = threadIdx.x;
  const int rowBase = blockIdx.x * 64;
  const int colBase = blockIdx.y * 128;
  const int wave = tid >> 6;
  const int lane = tid & 63;
  const int m16 = lane & 15;
  const int quad = lane >> 4;
  const size_t Mstride = (size_t)M * 128;

  floatx4 acc[8];
#pragma unroll
  for (int c = 0; c < 8; ++c)
#pragma unroll
    for (int r = 0; r < 4; ++r) acc[c][r] = 0.f;

  const int sRow = tid >> 2;
  const int sK8 = (tid & 3) * 8;
  const int growA = rowBase + sRow;
  const bool aValid = growA < M;

  for (int kc = 0; kc < 24; ++kc) {
    uint4 av = make_uint4(0, 0, 0, 0);
    if (aValid)
      av = *(const uint4*)(Tbf + (size_t)(kc >> 2) * Mstride + (size_t)growA * 128
                           + ((kc & 3) << 5) + sK8);
    *(uint4*)&Al[sRow][sK8] = av;
#pragma unroll
    for (int l = 0; l < 2; ++l) {
      int lin = tid + l * 256;
      int bRow = lin >> 2;
      int bK8 = (lin & 3) * 8;
      *(uint4*)&Bl[bRow][bK8] =
          *(const uint4*)(Wt + (size_t)(colBase + bRow) * 768 + kc * 32 + bK8);
    }
    __syncthreads();

    short8 a = *(const short8*)&Al[wave * 16 + m16][quad * 8];
#pragma unroll
    for (int c = 0; c < 8; ++c) {
      short8 b = *(const short8*)&Bl[c * 16 + m16][quad * 8];
      acc[c] = __builtin_amdgcn_mfma_f32_16x16x32_bf16(a, b, acc[c], 0, 0, 0);
    }
    __syncthreads();
  }

#pragma unroll
  for (int c = 0; c < 8; ++c) {
    int col = colBase + c * 16 + m16;
    float bv = bias[col];
#pragma unroll
    for (int r = 0; r < 4; ++r) {
      int row = rowBase + wave * 16 + quad * 4 + r;
      if (row < M) {
        float v = acc[c][r] + bv;
        if (RELU) v = fmaxf(v, 0.f);
        C[(size_t)row * N + col] = v;
      }
    }
  }
}

// ---------------- linear head ----------------
__global__ void initout_kernel(float* __restrict__ out, const float* __restrict__ linb) {
  int i = threadIdx.x;
  if (i < 10) out[i] = linb[i];
}

__global__ __launch_bounds__(256) void linear_kernel(const float* __restrict__ Wl,
                                                     const float* __restrict__ h,
                                                     float* __restrict__ out, int D) {
  float p[10];
#pragma unroll
  for (int j = 0; j < 10; ++j) p[j] = 0.f;
  int stride = gridDim.x * blockDim.x;
  for (int i = blockIdx.x * blockDim.x + threadIdx.x; i < D; i += stride) {
    float hv = h[i];
#pragma unroll
    for (int j = 0; j < 10; ++j) p[j] += Wl[(size_t)j * D + i] * hv;
  }
#pragma unroll
  for (int j = 0; j < 10; ++j) {
#pragma unroll
    for (int off = 32; off > 0; off >>= 1) p[j] += __shfl_down(p[j], off, 64);
  }
  __shared__ float s[4][10];
  int wave = threadIdx.x >> 6, lane = threadIdx.x & 63;
  if (lane == 0) {
#pragma unroll
    for (int j = 0; j < 10; ++j) s[wave][j] = p[j];
  }
  __syncthreads();
  if (threadIdx.x < 10) {
    float t = s[0][threadIdx.x] + s[1][threadIdx.x] + s[2][threadIdx.x] + s[3][threadIdx.x];
    atomicAdd(&out[threadIdx.x], t);
  }
}

// ---------------- host orchestration ----------------
extern "C" void kernel_launch(void* const* d_in, const int* in_sizes, int n_in,
                              void* d_out, int out_size, void* d_ws, size_t ws_size,
                              hipStream_t stream) {
  const float* x    = (const float*)d_in[0];
  const int*   ei0  = (const int*)d_in[1];
  const int*   ei1  = (const int*)d_in[2];
  const int*   ei2  = (const int*)d_in[3];
  const float* W0   = (const float*)d_in[4];
  const float* b0   = (const float*)d_in[5];
  const float* W1   = (const float*)d_in[6];
  const float* b1   = (const float*)d_in[7];
  const float* W2   = (const float*)d_in[8];
  const float* b2   = (const float*)d_in[9];
  const int*   D0r  = (const int*)d_in[10];
  const int*   D0c  = (const int*)d_in[11];
  const float* D0v  = (const float*)d_in[12];
  const int*   D1r  = (const int*)d_in[13];
  const int*   D1c  = (const int*)d_in[14];
  const float* D1v  = (const float*)d_in[15];
  const float* linW = (const float*)d_in[16];
  const float* linb = (const float*)d_in[17];
  float* out = (float*)d_out;
  (void)in_sizes; (void)n_in; (void)out_size; (void)ws_size;

  const int* src0 = ei0;            const int* dst0 = ei0 + cE0;
  const int* src1 = ei1;            const int* dst1 = ei1 + cE1;
  const int* src2 = ei2;            const int* dst2 = ei2 + cE2;

  float* ws = (float*)d_ws;
  size_t off = 0;
  auto alloc = [&](size_t n) {
    float* p = ws + off;
    off += (n + 63) & ~size_t(63);
    return p;
  };
  float* dinv       = alloc(DEG_TOTAL);
  int*   cntCB      = (int*)alloc((size_t)TCB * BSTRIDE);
  int*   bucketTot  = (int*)alloc(TB);
  int*   bucketBase = (int*)alloc(TB);
  int*   scatSrc    = (int*)alloc(S_TOTAL);
  int2*  scatPairs  = (int2*)alloc((size_t)2 * E_TOTAL);
  int2*  csrPairs   = (int2*)alloc((size_t)2 * E_TOTAL);
  int*   offArr     = (int*)alloc(NPAD_TOTAL);
  ushort* Wt1       = (ushort*)alloc(768 * 128 / 2);
  ushort* Wt2       = (ushort*)alloc(768 * 256 / 2);
  float4* Tb0       = (float4*)alloc((size_t)6 * cN0 * 4);
  float* Tlvl1      = alloc((size_t)6 * cN1 * 128);
  ushort* Tbf1      = (ushort*)alloc((size_t)6 * cN1 * 64);
  float* out1       = alloc((size_t)cN1 * 128);
  float* Tlvl2      = alloc((size_t)6 * cN2 * 128);
  ushort* Tbf2      = (ushort*)alloc((size_t)6 * cN2 * 64);
  float* out2       = alloc((size_t)cN2 * 256);

  auto nb = [](long long n) { return (unsigned)((n + 255) / 256); };

  // ---- atomic-free CSR build ----
  c1_count_kernel<<<TCB, 256, 0, stream>>>(dst0, dst1, dst2, D0r, D1r,
                                           src0, src1, src2, cntCB);
  c2a_scan_kernel<<<TB, 256, 0, stream>>>(cntCB, bucketTot);
  c2b_scan_kernel<<<8, 256, 0, stream>>>(bucketTot, bucketBase);
  c3_src_kernel<<<TCB - JCBASE[5], 256, 0, stream>>>(src0, src1, src2,
                                                     cntCB, bucketBase, scatSrc);
  ddeg_kernel<<<TB - JBBASE[5], 256, 0, stream>>>(scatSrc, bucketTot, bucketBase, dinv);
  c3_dst_kernel<<<JCBASE[5], 256, 0, stream>>>(dst0, src0, dst1, src1, dst2, src2,
                                               D0r, D0c, D0v, D1r, D1c, D1v,
                                               dinv, cntCB, bucketBase, scatPairs);
  dcsr_kernel<<<JBBASE[5], 256, 0, stream>>>(scatPairs, bucketTot, bucketBase,
                                             offArr, csrPairs);
  prep_w_kernel<<<nb(768 * 384), 256, 0, stream>>>(W1, W2, Wt1, Wt2);

  auto seg_off   = [&](int s) { return offArr + NBASE[s]; };
  auto seg_pairs = [&](int s) { return csrPairs + EBASE[s]; };

  // ================= Level 0 (F=3 -> 128, fused with pool0) =================
  copyx_kernel<<<nb(cN0), 256, 0, stream>>>(x, Tb0, cN0);
  {
    auto Tk = [&](int k) { return Tb0 + (size_t)k * cN0; };
    csr_prop3_kernel<<<nb(cN0), 256, 0, stream>>>(seg_off(0), seg_pairs(0),
        Tk(0), Tk(1), nullptr, 1.f, cN0);
    csr_prop3_kernel<<<nb(cN0), 256, 0, stream>>>(seg_off(0), seg_pairs(0),
        Tk(1), Tk(2), Tk(0), 2.f, cN0);
    csr_prop3_kernel<<<nb(cN0), 256, 0, stream>>>(seg_off(0), seg_pairs(0),
        Tk(2), Tk(3), Tk(1), 2.f, cN0);
    csr_prop3_kernel<<<nb(cN0), 256, 0, stream>>>(seg_off(0), seg_pairs(0),
        Tk(3), Tk(4), Tk(2), 2.f, cN0);
    csr_prop3_kernel<<<nb(cN0), 256, 0, stream>>>(seg_off(0), seg_pairs(0),
        Tk(4), Tk(5), Tk(3), 2.f, cN0);
  }
  // fused gemm18 + pool0 -> Tlvl1 block 0 (fp32 + bf16)
  g18pool_kernel<<<(cN1 + 1) / 2, 256, 0, stream>>>(
      seg_off(3), seg_pairs(3), Tb0, W0, b0, Tlvl1, Tbf1, cN1, cN0);

  // ================= Level 1 =================
  {
    auto Tk  = [&](int k) { return Tlvl1 + (size_t)k * cN1 * 128; };
    auto Tbk = [&](int k) { return Tbf1 + (size_t)k * cN1 * 128; };
    auto prop = [&](int kin, int kout, int kprev, float scale) {
      csr_prop128_kernel<<<(cN1 + 7) / 8, 256, 0, stream>>>(
          seg_off(1), seg_pairs(1), Tk(kin), Tk(kout), Tbk(kout),
          (kprev >= 0) ? Tk(kprev) : nullptr, scale, cN1);
    };
    prop(0, 1, -1, 1.f);
    prop(1, 2, 0, 2.f);
    prop(2, 3, 1, 2.f);
    prop(3, 4, 2, 2.f);
    prop(4, 5, 3, 2.f);
    dim3 g((cN1 + 63) / 64, 1);
    gemm_mfma_kernel<1><<<g, 256, 0, stream>>>(Tbf1, Wt1, b1, out1, cN1, 128);
  }

  // pool1: out1 -> Tlvl2 block 0 (fp32 + bf16)
  csr_prop128_kernel<<<(cN2 + 7) / 8, 256, 0, stream>>>(
      seg_off(4), seg_pairs(4), out1, Tlvl2, Tbf2, nullptr, 1.f, cN2);

  // ================= Level 2 (no relu, N=256) =================
  {
    auto Tk  = [&](int k) { return Tlvl2 + (size_t)k * cN2 * 128; };
    auto Tbk = [&](int k) { return Tbf2 + (size_t)k * cN2 * 128; };
    auto prop = [&](int kin, int kout, int kprev, float scale) {
      csr_prop128_kernel<<<(cN2 + 7) / 8, 256, 0, stream>>>(
          seg_off(2), seg_pairs(2), Tk(kin), Tk(kout), Tbk(kout),
          (kprev >= 0) ? Tk(kprev) : nullptr, scale, cN2);
    };
    prop(0, 1, -1, 1.f);
    prop(1, 2, 0, 2.f);
    prop(2, 3, 1, 2.f);
    prop(3, 4, 2, 2.f);
    prop(4, 5, 3, 2.f);
    dim3 g((cN2 + 63) / 64, 2);
    gemm_mfma_kernel<0><<<g, 256, 0, stream>>>(Tbf2, Wt2, b2, out2, cN2, 256);
  }

  // ---- linear head ----
  initout_kernel<<<1, 64, 0, stream>>>(out, linb);
  linear_kernel<<<512, 256, 0, stream>>>(linW, out2, out, cD);
}